// Round 15
// baseline (231.159 us; speedup 1.0000x reference)
//
#include <hip/hip_runtime.h>
#include <hip/hip_bf16.h>

#define N_NODES 100000
#define N_EDGES 1600000
#define D 128
#define BSZ 128                         // dst nodes per bucket
#define NBUCK 782                       // ceil(N_NODES / BSZ)
#define EPW 8192                        // edges per WG in hist/scatter
#define NWG1 ((N_EDGES + EPW - 1) / EPW)  // 196
#define CAP 4096                        // LDS edge staging per bucket (mean 2048)
#define OTS 272                         // epilogue LDS tile row stride (bytes)
#define PLANE ((size_t)N_NODES * 64)    // fp16 elements per column-plane (12.8 MB)

typedef unsigned int  uint4n  __attribute__((ext_vector_type(4)));
typedef float         float4n __attribute__((ext_vector_type(4)));
typedef _Float16      half8n  __attribute__((ext_vector_type(8)));
typedef _Float16      half4n  __attribute__((ext_vector_type(4)));

// swizzled LDS byte offset for element (row, kb): 256B per row, XOR bits 4-7
#define SWZ(row, kb) (((row) << 8) + ((kb) ^ (((row) & 15) << 4)))

// tanh(x) = 1 - 2/(exp2(2*log2e*x)+1); hw exp2+rcp, abs err ~2e-7.
__device__ __forceinline__ float fast_tanh(float x) {
    float t = __builtin_amdgcn_exp2f(x * 2.885390081777927f);
    return 1.0f - 2.0f * __builtin_amdgcn_rcpf(t + 1.0f);
}

// ---------------- W prep (+ bcnt zero in block 32) ----------------
// Element W[k][c] lands at byte SWZ(c, 2k) of its 32KB blob.
__global__ __launch_bounds__(256) void k_wprep(const float* __restrict__ W1,
                                               const float* __restrict__ W2,
                                               char* __restrict__ Wt,
                                               int* __restrict__ bcnt) {
    if (blockIdx.x == 32) {
        for (int i = threadIdx.x; i < NBUCK; i += 256) bcnt[i] = 0;
        return;
    }
    const float* W = (blockIdx.x < 16) ? W1 : W2;
    char* dst = Wt + ((blockIdx.x < 16) ? 0 : 32768);
    int t = (blockIdx.x & 15) * 256 + threadIdx.x;   // 0..4095
    int idx = t * 4;
    int k = idx >> 7, c = idx & 127;
    float4 wv = *(const float4*)&W[idx];
    *(_Float16*)(dst + SWZ(c + 0, k * 2)) = (_Float16)wv.x;
    *(_Float16*)(dst + SWZ(c + 1, k * 2)) = (_Float16)wv.y;
    *(_Float16*)(dst + SWZ(c + 2, k * 2)) = (_Float16)wv.z;
    *(_Float16*)(dst + SWZ(c + 3, k * 2)) = (_Float16)wv.w;
}

// ---------------- stage 0: bucket histogram (LDS-staged, low contention) ----------------

__global__ __launch_bounds__(256) void k_hist1(const int* __restrict__ dst,
                                               int* __restrict__ bcnt) {
    __shared__ int h[NBUCK];
    for (int i = threadIdx.x; i < NBUCK; i += 256) h[i] = 0;
    __syncthreads();
    int base = blockIdx.x * EPW;
    int end  = min(base + EPW, N_EDGES);
    for (int i = base + threadIdx.x; i < end; i += 256)
        atomicAdd(&h[dst[i] >> 7], 1);
    __syncthreads();
    for (int i = threadIdx.x; i < NBUCK; i += 256)
        if (h[i]) atomicAdd(&bcnt[i], h[i]);
}

// Single-block exclusive scan over NBUCK counts -> boff & gcur.
__global__ void k_scanN(const int* __restrict__ bcnt, int* __restrict__ boff,
                        int* __restrict__ gcur) {
    __shared__ int tmp[256];
    int tid = threadIdx.x;
    int carry = 0;
    for (int c = 0; c < (NBUCK + 255) / 256; c++) {
        int i = c * 256 + tid;
        int v = (i < NBUCK) ? bcnt[i] : 0;
        tmp[tid] = v;
        __syncthreads();
        int run = v;
        for (int off = 1; off < 256; off <<= 1) {
            int t = (tid >= off) ? tmp[tid - off] : 0;
            __syncthreads();
            run += t;
            tmp[tid] = run;
            __syncthreads();
        }
        int excl = carry + run - v;
        if (i < NBUCK) { boff[i] = excl; gcur[i] = excl; }
        int tot = tmp[255];
        __syncthreads();
        carry += tot;
    }
    if (tid == 0) boff[NBUCK] = N_EDGES;
}

// ---------------- stage 1: bucket scatter (bulk reservation, dense runs) ----------------
// Payload: (src<<8 | dst&127, weight) = 8B; src<<8 IS the byte offset of a 256B row.
__global__ __launch_bounds__(256) void k_scat1(const int* __restrict__ src,
                                               const int* __restrict__ dst,
                                               const float* __restrict__ ew,
                                               int* __restrict__ gcur,
                                               int2* __restrict__ ebuf) {
    __shared__ int h[NBUCK];
    __shared__ int rb[NBUCK];
    for (int i = threadIdx.x; i < NBUCK; i += 256) h[i] = 0;
    __syncthreads();
    int base = blockIdx.x * EPW;
    int end  = min(base + EPW, N_EDGES);
    for (int i = base + threadIdx.x; i < end; i += 256)
        atomicAdd(&h[dst[i] >> 7], 1);
    __syncthreads();
    for (int i = threadIdx.x; i < NBUCK; i += 256) {
        int c = h[i];
        if (c) rb[i] = atomicAdd(&gcur[i], c);   // reserve contiguous range
    }
    __syncthreads();
    for (int i = base + threadIdx.x; i < end; i += 256) {
        int d  = dst[i];
        int bk = d >> 7;
        int p  = atomicAdd(&rb[bk], 1);          // LDS int cursor (native, fast)
        ebuf[p] = make_int2((src[i] << 8) | (d & 127), __float_as_int(ew[i]));
    }
}

// ---------------- stage 2: per-bucket counting sort (in-place via LDS) + rowptr ----------------
__global__ __launch_bounds__(512) void k_sortb(int2* __restrict__ ebuf,
                                               const int* __restrict__ boff,
                                               int* __restrict__ rowptr) {
    __shared__ int2 se[CAP];
    __shared__ int cnt[BSZ];
    __shared__ int cur[BSZ];
    int tid = threadIdx.x;
    int b   = blockIdx.x;
    int e0 = boff[b], e1 = boff[b + 1];
    int m  = e1 - e0;
    if (tid < BSZ) cnt[tid] = 0;
    __syncthreads();
    int2 ovf;
    bool hasOvf = false;
    for (int i = tid; i < m; i += 512) {          // all GLOBAL reads happen here
        int2 v = ebuf[e0 + i];
        if (i < CAP) se[i] = v;
        else { ovf = v; hasOvf = true; }          // statistically never (m~2048±45)
        atomicAdd(&cnt[v.x & (BSZ - 1)], 1);
    }
    __syncthreads();
    if (tid < 64) {                               // wave-0 shfl scan of 128 counts
        int a  = cnt[tid * 2], bq = cnt[tid * 2 + 1];
        int s  = a + bq;
        int incl = s;
        #pragma unroll
        for (int off = 1; off < 64; off <<= 1) {
            int t = __shfl_up(incl, off, 64);
            if (tid >= off) incl += t;
        }
        int ex = incl - s;                        // exclusive prefix of this pair
        cur[tid * 2]     = ex;
        cur[tid * 2 + 1] = ex + a;
        int node = b * BSZ + tid * 2;
        if (node     <= N_NODES) rowptr[node]     = e0 + ex;
        if (node + 1 <= N_NODES) rowptr[node + 1] = e0 + ex + a;
    }
    __syncthreads();
    for (int i = tid; i < m && i < CAP; i += 512) {
        int2 v = se[i];
        int p = atomicAdd(&cur[v.x & (BSZ - 1)], 1);
        ebuf[e0 + p] = v;
    }
    if (hasOvf) {
        int p = atomicAdd(&cur[ovf.x & (BSZ - 1)], 1);
        ebuf[e0 + p] = ovf;
    }
}

// ---------------- GEMM (MFMA): H[n x 128](fp16, column-split planes) = X @ W ----------------
// 1563 blocks x 256 thr (4 waves). Block = 64-row slab, all 128 cols.
// H (and fp16 X input) layout: plane p (cols p*64..+63) at base + p*PLANE, row stride 64.
template<bool XF16>
__global__ __launch_bounds__(256) void k_gemm(const void* __restrict__ Xv,
                                              const char* __restrict__ Wt,
                                              _Float16* __restrict__ H, int n) {
    __shared__ char smem[17408];                  // 64*OTS; staging uses first 16KB
    char* sA = smem;
    int tid  = threadIdx.x;
    int lane = tid & 63, w = tid >> 6;
    int rows0 = blockIdx.x * 64;

    int rb = (w >> 1) * 32;      // wave row base within slab (0/32)
    int cb = (w & 1) * 64;       // wave col base (0/64)
    int lr = lane & 15;          // frag row/col within tile
    int kg = (lane >> 4) * 16;   // k-group byte offset ((lane>>4)*8 halves)

    // --- stage A slab (fp16, swizzled): 64 rows x 128 cols ---
    if (XF16) {
        const _Float16* Xh = (const _Float16*)Xv;
        #pragma unroll
        for (int rep = 0; rep < 4; rep++) {
            int ef = rep * 2048 + tid * 8;       // element index r*128+c
            int r = ef >> 7, c = ef & 127;
            int rg = rows0 + r;
            half8n v = half8n(0);
            if (rg < n)
                v = *(const half8n*)(Xh + (size_t)(c >> 6) * PLANE + (size_t)rg * 64 + (c & 63));
            *(half8n*)(sA + SWZ(r, c * 2)) = v;
        }
    } else {
        const float* Xf = (const float*)Xv;
        #pragma unroll
        for (int rep = 0; rep < 8; rep++) {
            int ef = rep * 1024 + tid * 4;
            int r = ef >> 7, c = ef & 127;
            int rg = rows0 + r;
            float4 xv = make_float4(0.f, 0.f, 0.f, 0.f);
            if (rg < n) xv = *(const float4*)(Xf + (size_t)rg * 128 + c);
            half4n hv;
            hv[0] = (_Float16)xv.x; hv[1] = (_Float16)xv.y;
            hv[2] = (_Float16)xv.z; hv[3] = (_Float16)xv.w;
            *(half4n*)(sA + SWZ(r, c * 2)) = hv;
        }
    }
    __syncthreads();

    float4n acc[2][4] = {};
    #pragma unroll
    for (int ks = 0; ks < 4; ks++) {
        half8n bwk[4];
        #pragma unroll
        for (int ct = 0; ct < 4; ct++)
            bwk[ct] = *(const half8n*)(Wt + SWZ(cb + ct * 16 + lr, ks * 64 + kg));
        half8n af[2];
        #pragma unroll
        for (int rt = 0; rt < 2; rt++)
            af[rt] = *(const half8n*)(sA + SWZ(rb + rt * 16 + lr, ks * 64 + kg));
        #pragma unroll
        for (int rt = 0; rt < 2; rt++)
            #pragma unroll
            for (int ct = 0; ct < 4; ct++)
                acc[rt][ct] = __builtin_amdgcn_mfma_f32_16x16x32_f16(af[rt], bwk[ct], acc[rt][ct], 0, 0, 0);
    }

    // --- epilogue: acc -> LDS tile -> coalesced split-plane stores ---
    __syncthreads();                              // sA dead, reuse as OT
    char* OT = smem;                              // 64 rows x OTS bytes
    int rloc = rb + (lane >> 4) * 4;              // local row base
    #pragma unroll
    for (int rt = 0; rt < 2; rt++) {
        #pragma unroll
        for (int ct = 0; ct < 4; ct++) {
            int col = cb + ct * 16 + lr;
            #pragma unroll
            for (int r = 0; r < 4; r++)
                *(_Float16*)(OT + (rloc + rt * 16 + r) * OTS + col * 2) = (_Float16)acc[rt][ct][r];
        }
    }
    __syncthreads();
    #pragma unroll
    for (int rep = 0; rep < 4; rep++) {
        int ef = rep * 2048 + tid * 8;
        int r = ef >> 7, c = ef & 127;
        int rg = rows0 + r;
        if (rg < n) {
            half8n v = *(const half8n*)(OT + r * OTS + c * 2);
            *(half8n*)(H + (size_t)(c >> 6) * PLANE + (size_t)rg * 64 + (c & 63)) = v;
        }
    }
}

// ---------------- Aggregation: out[n] = tanh(sum_e w_e * H[src_e]) ----------------
// Column-split: blockIdx.y = pass (plane). Each pass gathers 128B/edge from a
// 12.8MB plane (2x L2 hit rate). 4 nodes/wave, 16 lanes/node, 8B/lane.
// 4 gathers in flight per inner iteration.
template<bool OUTF16>
__global__ __launch_bounds__(256) void k_agg(const _Float16* __restrict__ H,
                                             const int* __restrict__ rowptr,
                                             const int2* __restrict__ ebuf,
                                             void* __restrict__ outv, int n) {
    int wv   = (blockIdx.x * 256 + threadIdx.x) >> 6;   // global wave index
    int lane = threadIdx.x & 63;
    int pass = blockIdx.y;
    int g = lane >> 4;                 // node slot within wave (0..3)
    int c = lane & 15;                 // column quad: cols c*4..c*4+3 of the plane
    int node = wv * 4 + g;
    if (node >= n) return;
    const char* Hc = (const char*)(H + (size_t)pass * PLANE) + c * 8;  // 8B/lane
    int e0 = rowptr[node], e1 = rowptr[node + 1];
    float acc[4] = {};
    int e = e0;
    for (; e + 4 <= e1; e += 4) {                 // 4 gathers in flight
        int2 d0 = ebuf[e];
        int2 d1 = ebuf[e + 1];
        int2 d2 = ebuf[e + 2];
        int2 d3 = ebuf[e + 3];
        // plane row byte offset = src*128 = (rec.x & ~255) >> 1
        half4n v0 = *(const half4n*)(Hc + ((size_t)((unsigned)d0.x & 0xFFFFFF00u) >> 1));
        half4n v1 = *(const half4n*)(Hc + ((size_t)((unsigned)d1.x & 0xFFFFFF00u) >> 1));
        half4n v2 = *(const half4n*)(Hc + ((size_t)((unsigned)d2.x & 0xFFFFFF00u) >> 1));
        half4n v3 = *(const half4n*)(Hc + ((size_t)((unsigned)d3.x & 0xFFFFFF00u) >> 1));
        float w0 = __int_as_float(d0.y);
        float w1 = __int_as_float(d1.y);
        float w2 = __int_as_float(d2.y);
        float w3 = __int_as_float(d3.y);
        #pragma unroll
        for (int j = 0; j < 4; j++) acc[j] = __builtin_fmaf((float)v0[j], w0, acc[j]);
        #pragma unroll
        for (int j = 0; j < 4; j++) acc[j] = __builtin_fmaf((float)v1[j], w1, acc[j]);
        #pragma unroll
        for (int j = 0; j < 4; j++) acc[j] = __builtin_fmaf((float)v2[j], w2, acc[j]);
        #pragma unroll
        for (int j = 0; j < 4; j++) acc[j] = __builtin_fmaf((float)v3[j], w3, acc[j]);
    }
    for (; e < e1; ++e) {
        int2 ed = ebuf[e];
        half4n v = *(const half4n*)(Hc + ((size_t)((unsigned)ed.x & 0xFFFFFF00u) >> 1));
        float w = __int_as_float(ed.y);
        #pragma unroll
        for (int j = 0; j < 4; j++) acc[j] = __builtin_fmaf((float)v[j], w, acc[j]);
    }
    if (OUTF16) {
        half4n hv;
        #pragma unroll
        for (int j = 0; j < 4; j++) hv[j] = (_Float16)fast_tanh(acc[j]);
        // split-plane store, contiguous 128B per node per pass; cache-resident for GEMM-2
        *(half4n*)((_Float16*)outv + (size_t)pass * PLANE + (size_t)node * 64 + c * 4) = hv;
    } else {
        float4n o;
        o.x = fast_tanh(acc[0]); o.y = fast_tanh(acc[1]);
        o.z = fast_tanh(acc[2]); o.w = fast_tanh(acc[3]);
        __builtin_nontemporal_store(o,
            (float4n*)((float*)outv + (size_t)node * 128 + pass * 64 + c * 4));
    }
}

// ---------------- launch ----------------

extern "C" void kernel_launch(void* const* d_in, const int* in_sizes, int n_in,
                              void* d_out, int out_size, void* d_ws, size_t ws_size,
                              hipStream_t stream) {
    const float* x    = (const float*)d_in[0];
    const int*   esrc = (const int*)d_in[1];
    const int*   edst = (const int*)d_in[2];
    const float* ew   = (const float*)d_in[3];
    const float* W1   = (const float*)d_in[4];
    const float* W2   = (const float*)d_in[5];
    float* out = (float*)d_out;

    // Workspace layout (~64.6 MB):
    _Float16* hbuf = (_Float16*)d_ws;                      // N*D fp16, 2 planes (25.6 MB)
    _Float16* act1 = hbuf + 2 * PLANE;                     // N*D fp16, 2 planes (25.6 MB)
    int2* ebuf     = (int2*)(act1 + 2 * PLANE);            // E int2 (12.8 MB), 8B-aligned
    int*  bcnt     = (int*)(ebuf + N_EDGES);               // NBUCK
    int*  boff     = bcnt + NBUCK;                         // NBUCK+1
    int*  gcur     = boff + (NBUCK + 1);                   // NBUCK
    int*  rowptr   = gcur + NBUCK;                         // N+1 ints (0.4 MB)
    char* Wt       = (char*)(rowptr + N_NODES + 8);        // 64 KB (two 32KB blobs)
    (void)ws_size; (void)in_sizes; (void)n_in; (void)out_size;

    // --- W prep (+bcnt zero) + CSR build (graph identical for both layers) ---
    k_wprep<<<33, 256, 0, stream>>>(W1, W2, Wt, bcnt);
    k_hist1<<<NWG1, 256, 0, stream>>>(edst, bcnt);
    k_scanN<<<1, 256, 0, stream>>>(bcnt, boff, gcur);
    k_scat1<<<NWG1, 256, 0, stream>>>(esrc, edst, ew, gcur, ebuf);
    k_sortb<<<NBUCK, 512, 0, stream>>>(ebuf, boff, rowptr);

    int gemm_blocks = (N_NODES + 63) / 64;                  // 1563
    dim3 gga((N_NODES + 15) / 16, 2);                       // 4 nodes/wave x 2 passes

    // --- layer 1 ---
    k_gemm<false><<<gemm_blocks, 256, 0, stream>>>(x, Wt, hbuf, N_NODES);
    k_agg<true><<<gga, 256, 0, stream>>>(hbuf, rowptr, ebuf, act1, N_NODES);
    // --- layer 2 ---
    k_gemm<true><<<gemm_blocks, 256, 0, stream>>>(act1, Wt + 32768, hbuf, N_NODES);
    k_agg<false><<<gga, 256, 0, stream>>>(hbuf, rowptr, ebuf, out, N_NODES);
}

// Round 16
// 230.527 us; speedup vs baseline: 1.0027x; 1.0027x over previous
//
#include <hip/hip_runtime.h>
#include <hip/hip_bf16.h>

#define N_NODES 100000
#define N_EDGES 1600000
#define D 128
#define BSZ 128                         // dst nodes per bucket
#define NBUCK 782                       // ceil(N_NODES / BSZ)
#define EPW 8192                        // edges per WG in hist/scatter
#define NWG1 ((N_EDGES + EPW - 1) / EPW)  // 196
#define CAP 4096                        // LDS edge staging per bucket (mean 2048)
#define OTS 272                         // epilogue LDS tile row stride (bytes)

typedef unsigned int  uint4n  __attribute__((ext_vector_type(4)));
typedef float         float4n __attribute__((ext_vector_type(4)));
typedef _Float16      half8n  __attribute__((ext_vector_type(8)));
typedef _Float16      half4n  __attribute__((ext_vector_type(4)));

// swizzled LDS byte offset for element (row, kb): 256B per row, XOR bits 4-7
#define SWZ(row, kb) (((row) << 8) + ((kb) ^ (((row) & 15) << 4)))

// tanh(x) = 1 - 2/(exp2(2*log2e*x)+1); hw exp2+rcp, abs err ~2e-7.
__device__ __forceinline__ float fast_tanh(float x) {
    float t = __builtin_amdgcn_exp2f(x * 2.885390081777927f);
    return 1.0f - 2.0f * __builtin_amdgcn_rcpf(t + 1.0f);
}

// ---------------- W prep (+ bcnt zero in block 32) ----------------
// Element W[k][c] lands at byte SWZ(c, 2k) of its 32KB blob.
__global__ __launch_bounds__(256) void k_wprep(const float* __restrict__ W1,
                                               const float* __restrict__ W2,
                                               char* __restrict__ Wt,
                                               int* __restrict__ bcnt) {
    if (blockIdx.x == 32) {
        for (int i = threadIdx.x; i < NBUCK; i += 256) bcnt[i] = 0;
        return;
    }
    const float* W = (blockIdx.x < 16) ? W1 : W2;
    char* dst = Wt + ((blockIdx.x < 16) ? 0 : 32768);
    int t = (blockIdx.x & 15) * 256 + threadIdx.x;   // 0..4095
    int idx = t * 4;
    int k = idx >> 7, c = idx & 127;
    float4 wv = *(const float4*)&W[idx];
    *(_Float16*)(dst + SWZ(c + 0, k * 2)) = (_Float16)wv.x;
    *(_Float16*)(dst + SWZ(c + 1, k * 2)) = (_Float16)wv.y;
    *(_Float16*)(dst + SWZ(c + 2, k * 2)) = (_Float16)wv.z;
    *(_Float16*)(dst + SWZ(c + 3, k * 2)) = (_Float16)wv.w;
}

// ---------------- stage 0: bucket histogram (LDS-staged, low contention) ----------------

__global__ __launch_bounds__(256) void k_hist1(const int* __restrict__ dst,
                                               int* __restrict__ bcnt) {
    __shared__ int h[NBUCK];
    for (int i = threadIdx.x; i < NBUCK; i += 256) h[i] = 0;
    __syncthreads();
    int base = blockIdx.x * EPW;
    int end  = min(base + EPW, N_EDGES);
    for (int i = base + threadIdx.x; i < end; i += 256)
        atomicAdd(&h[dst[i] >> 7], 1);
    __syncthreads();
    for (int i = threadIdx.x; i < NBUCK; i += 256)
        if (h[i]) atomicAdd(&bcnt[i], h[i]);
}

// Single-block exclusive scan over NBUCK counts -> boff & gcur.
__global__ void k_scanN(const int* __restrict__ bcnt, int* __restrict__ boff,
                        int* __restrict__ gcur) {
    __shared__ int tmp[256];
    int tid = threadIdx.x;
    int carry = 0;
    for (int c = 0; c < (NBUCK + 255) / 256; c++) {
        int i = c * 256 + tid;
        int v = (i < NBUCK) ? bcnt[i] : 0;
        tmp[tid] = v;
        __syncthreads();
        int run = v;
        for (int off = 1; off < 256; off <<= 1) {
            int t = (tid >= off) ? tmp[tid - off] : 0;
            __syncthreads();
            run += t;
            tmp[tid] = run;
            __syncthreads();
        }
        int excl = carry + run - v;
        if (i < NBUCK) { boff[i] = excl; gcur[i] = excl; }
        int tot = tmp[255];
        __syncthreads();
        carry += tot;
    }
    if (tid == 0) boff[NBUCK] = N_EDGES;
}

// ---------------- stage 1: bucket scatter (bulk reservation, dense runs) ----------------
// Payload: (src<<8 | dst&127, weight) = 8B; src<<8 IS the byte offset of H row.
__global__ __launch_bounds__(256) void k_scat1(const int* __restrict__ src,
                                               const int* __restrict__ dst,
                                               const float* __restrict__ ew,
                                               int* __restrict__ gcur,
                                               int2* __restrict__ ebuf) {
    __shared__ int h[NBUCK];
    __shared__ int rb[NBUCK];
    for (int i = threadIdx.x; i < NBUCK; i += 256) h[i] = 0;
    __syncthreads();
    int base = blockIdx.x * EPW;
    int end  = min(base + EPW, N_EDGES);
    for (int i = base + threadIdx.x; i < end; i += 256)
        atomicAdd(&h[dst[i] >> 7], 1);
    __syncthreads();
    for (int i = threadIdx.x; i < NBUCK; i += 256) {
        int c = h[i];
        if (c) rb[i] = atomicAdd(&gcur[i], c);   // reserve contiguous range
    }
    __syncthreads();
    for (int i = base + threadIdx.x; i < end; i += 256) {
        int d  = dst[i];
        int bk = d >> 7;
        int p  = atomicAdd(&rb[bk], 1);          // LDS int cursor (native, fast)
        ebuf[p] = make_int2((src[i] << 8) | (d & 127), __float_as_int(ew[i]));
    }
}

// ---------------- stage 2: per-bucket counting sort (in-place via LDS) + rowptr ----------------
__global__ __launch_bounds__(512) void k_sortb(int2* __restrict__ ebuf,
                                               const int* __restrict__ boff,
                                               int* __restrict__ rowptr) {
    __shared__ int2 se[CAP];
    __shared__ int cnt[BSZ];
    __shared__ int cur[BSZ];
    int tid = threadIdx.x;
    int b   = blockIdx.x;
    int e0 = boff[b], e1 = boff[b + 1];
    int m  = e1 - e0;
    if (tid < BSZ) cnt[tid] = 0;
    __syncthreads();
    int2 ovf;
    bool hasOvf = false;
    for (int i = tid; i < m; i += 512) {          // all GLOBAL reads happen here
        int2 v = ebuf[e0 + i];
        if (i < CAP) se[i] = v;
        else { ovf = v; hasOvf = true; }          // statistically never (m~2048±45)
        atomicAdd(&cnt[v.x & (BSZ - 1)], 1);
    }
    __syncthreads();
    if (tid < 64) {                               // wave-0 shfl scan of 128 counts
        int a  = cnt[tid * 2], bq = cnt[tid * 2 + 1];
        int s  = a + bq;
        int incl = s;
        #pragma unroll
        for (int off = 1; off < 64; off <<= 1) {
            int t = __shfl_up(incl, off, 64);
            if (tid >= off) incl += t;
        }
        int ex = incl - s;                        // exclusive prefix of this pair
        cur[tid * 2]     = ex;
        cur[tid * 2 + 1] = ex + a;
        int node = b * BSZ + tid * 2;
        if (node     <= N_NODES) rowptr[node]     = e0 + ex;
        if (node + 1 <= N_NODES) rowptr[node + 1] = e0 + ex + a;
    }
    __syncthreads();
    for (int i = tid; i < m && i < CAP; i += 512) {
        int2 v = se[i];
        int p = atomicAdd(&cur[v.x & (BSZ - 1)], 1);
        ebuf[e0 + p] = v;
    }
    if (hasOvf) {
        int p = atomicAdd(&cur[ovf.x & (BSZ - 1)], 1);
        ebuf[e0 + p] = ovf;
    }
}

// ---------------- GEMM (MFMA): H[n x 128](fp16) = X[n x 128] @ W[128 x 128] ----------------
// 1563 blocks x 256 thr (4 waves). Block = 64-row slab, all 128 cols.
// Wave (wr=w>>1, wc=w&1): rows wr*32..+32 (rt=2), cols wc*64..+64 (ct=4).
// W frags per-K-step from global pre-swizzled Wt (L2-hot).
// XF16 path: A-frags DIRECTLY from global (16B/lane contiguous) -> no staging, no barrier.
// F32 path (layer 1): staged via LDS with f32->f16 convert.
template<bool XF16>
__global__ __launch_bounds__(256) void k_gemm(const void* __restrict__ Xv,
                                              const char* __restrict__ Wt,
                                              _Float16* __restrict__ H, int n) {
    __shared__ char smem[17408];                  // 64*OTS; staging uses first 16KB
    char* sA = smem;
    int tid  = threadIdx.x;
    int lane = tid & 63, w = tid >> 6;
    int rows0 = blockIdx.x * 64;

    int rb = (w >> 1) * 32;      // wave row base within slab (0/32)
    int cb = (w & 1) * 64;       // wave col base (0/64)
    int lr = lane & 15;          // frag row/col within tile
    int kg = (lane >> 4) * 16;   // k-group byte offset ((lane>>4)*8 halves)

    float4n acc[2][4] = {};

    if (XF16) {
        // --- direct-from-global A-frags (no LDS, no barrier) ---
        const _Float16* Xh = (const _Float16*)Xv;
        const _Float16* Arow0 = Xh + (size_t)(rows0 + rb + lr) * 128 + (kg >> 1);
        #pragma unroll
        for (int ks = 0; ks < 4; ks++) {
            half8n bwk[4];
            #pragma unroll
            for (int ct = 0; ct < 4; ct++)
                bwk[ct] = *(const half8n*)(Wt + SWZ(cb + ct * 16 + lr, ks * 64 + kg));
            half8n af[2];
            #pragma unroll
            for (int rt = 0; rt < 2; rt++)
                af[rt] = *(const half8n*)(Arow0 + (size_t)rt * 16 * 128 + ks * 32);
            #pragma unroll
            for (int rt = 0; rt < 2; rt++)
                #pragma unroll
                for (int ct = 0; ct < 4; ct++)
                    acc[rt][ct] = __builtin_amdgcn_mfma_f32_16x16x32_f16(af[rt], bwk[ct], acc[rt][ct], 0, 0, 0);
        }
    } else {
        // --- stage A slab (f32 -> fp16, swizzled): 64 rows x 128 cols ---
        const float* Xf = (const float*)Xv;
        #pragma unroll
        for (int rep = 0; rep < 8; rep++) {
            int ef = rep * 1024 + tid * 4;
            int r = ef >> 7, c = ef & 127;
            int rg = rows0 + r;
            float4 xv = make_float4(0.f, 0.f, 0.f, 0.f);
            if (rg < n) xv = *(const float4*)(Xf + (size_t)rg * 128 + c);
            half4n hv;
            hv[0] = (_Float16)xv.x; hv[1] = (_Float16)xv.y;
            hv[2] = (_Float16)xv.z; hv[3] = (_Float16)xv.w;
            *(half4n*)(sA + SWZ(r, c * 2)) = hv;
        }
        __syncthreads();
        #pragma unroll
        for (int ks = 0; ks < 4; ks++) {
            half8n bwk[4];
            #pragma unroll
            for (int ct = 0; ct < 4; ct++)
                bwk[ct] = *(const half8n*)(Wt + SWZ(cb + ct * 16 + lr, ks * 64 + kg));
            half8n af[2];
            #pragma unroll
            for (int rt = 0; rt < 2; rt++)
                af[rt] = *(const half8n*)(sA + SWZ(rb + rt * 16 + lr, ks * 64 + kg));
            #pragma unroll
            for (int rt = 0; rt < 2; rt++)
                #pragma unroll
                for (int ct = 0; ct < 4; ct++)
                    acc[rt][ct] = __builtin_amdgcn_mfma_f32_16x16x32_f16(af[rt], bwk[ct], acc[rt][ct], 0, 0, 0);
        }
        __syncthreads();                          // sA dead before OT reuse
    }

    // --- epilogue: acc -> LDS tile -> coalesced stores ---
    char* OT = smem;                              // 64 rows x OTS bytes
    int rloc = rb + (lane >> 4) * 4;              // local row base
    #pragma unroll
    for (int rt = 0; rt < 2; rt++) {
        #pragma unroll
        for (int ct = 0; ct < 4; ct++) {
            int col = cb + ct * 16 + lr;
            #pragma unroll
            for (int r = 0; r < 4; r++)
                *(_Float16*)(OT + (rloc + rt * 16 + r) * OTS + col * 2) = (_Float16)acc[rt][ct][r];
        }
    }
    __syncthreads();
    #pragma unroll
    for (int rep = 0; rep < 4; rep++) {
        int ef = rep * 2048 + tid * 8;
        int r = ef >> 7, c = ef & 127;
        int rg = rows0 + r;
        if (rg < n) {
            half8n v = *(const half8n*)(OT + r * OTS + c * 2);
            *(half8n*)&H[(size_t)rg * 128 + c] = v;
        }
    }
}

// ---------------- Aggregation: out[n] = tanh(sum_e w_e * H[src_e]) ----------------
// FOUR nodes per wave (16-lane group per node). Inner loop keeps FOUR gathers
// in flight: load 4 edge records first, then issue 4 H-row gathers, then FMAs.
template<bool OUTF16>
__global__ __launch_bounds__(256) void k_agg(const _Float16* __restrict__ H,
                                             const int* __restrict__ rowptr,
                                             const int2* __restrict__ ebuf,
                                             void* __restrict__ outv, int n) {
    int wv   = (blockIdx.x * 256 + threadIdx.x) >> 6;   // global wave index
    int lane = threadIdx.x & 63;
    int g = lane >> 4;                 // node slot within wave (0..3)
    int c = lane & 15;                 // columns c*8 .. c*8+7 (16B of the row)
    int node = wv * 4 + g;
    if (node >= n) return;
    const char* Hc = (const char*)H + (c << 4);   // per-lane column base
    int e0 = rowptr[node], e1 = rowptr[node + 1];
    float acc[8] = {};
    int e = e0;
    for (; e + 4 <= e1; e += 4) {                 // 4 gathers in flight
        int2 d0 = ebuf[e];
        int2 d1 = ebuf[e + 1];
        int2 d2 = ebuf[e + 2];
        int2 d3 = ebuf[e + 3];
        half8n v0 = *(const half8n*)(Hc + (size_t)((unsigned)d0.x & 0xFFFFFF00u));
        half8n v1 = *(const half8n*)(Hc + (size_t)((unsigned)d1.x & 0xFFFFFF00u));
        half8n v2 = *(const half8n*)(Hc + (size_t)((unsigned)d2.x & 0xFFFFFF00u));
        half8n v3 = *(const half8n*)(Hc + (size_t)((unsigned)d3.x & 0xFFFFFF00u));
        float w0 = __int_as_float(d0.y);
        float w1 = __int_as_float(d1.y);
        float w2 = __int_as_float(d2.y);
        float w3 = __int_as_float(d3.y);
        #pragma unroll
        for (int j = 0; j < 8; j++) acc[j] = __builtin_fmaf((float)v0[j], w0, acc[j]);
        #pragma unroll
        for (int j = 0; j < 8; j++) acc[j] = __builtin_fmaf((float)v1[j], w1, acc[j]);
        #pragma unroll
        for (int j = 0; j < 8; j++) acc[j] = __builtin_fmaf((float)v2[j], w2, acc[j]);
        #pragma unroll
        for (int j = 0; j < 8; j++) acc[j] = __builtin_fmaf((float)v3[j], w3, acc[j]);
    }
    for (; e < e1; ++e) {
        int2 ed = ebuf[e];
        half8n v = *(const half8n*)(Hc + (size_t)((unsigned)ed.x & 0xFFFFFF00u));
        float w = __int_as_float(ed.y);
        #pragma unroll
        for (int j = 0; j < 8; j++) acc[j] = __builtin_fmaf((float)v[j], w, acc[j]);
    }
    if (OUTF16) {
        half8n hv;
        #pragma unroll
        for (int j = 0; j < 8; j++) hv[j] = (_Float16)fast_tanh(acc[j]);
        // plain store: act1 is re-read by the next GEMM, keep it cache-resident
        *(uint4n*)((_Float16*)outv + (size_t)node * 128 + c * 8) = *(uint4n*)&hv;
    } else {
        float* op = (float*)outv + (size_t)node * 128 + c * 8;
        float4n o0, o1;
        o0.x = fast_tanh(acc[0]); o0.y = fast_tanh(acc[1]);
        o0.z = fast_tanh(acc[2]); o0.w = fast_tanh(acc[3]);
        o1.x = fast_tanh(acc[4]); o1.y = fast_tanh(acc[5]);
        o1.z = fast_tanh(acc[6]); o1.w = fast_tanh(acc[7]);
        __builtin_nontemporal_store(o0, (float4n*)op);
        __builtin_nontemporal_store(o1, (float4n*)(op + 4));
    }
}

// ---------------- launch ----------------

extern "C" void kernel_launch(void* const* d_in, const int* in_sizes, int n_in,
                              void* d_out, int out_size, void* d_ws, size_t ws_size,
                              hipStream_t stream) {
    const float* x    = (const float*)d_in[0];
    const int*   esrc = (const int*)d_in[1];
    const int*   edst = (const int*)d_in[2];
    const float* ew   = (const float*)d_in[3];
    const float* W1   = (const float*)d_in[4];
    const float* W2   = (const float*)d_in[5];
    float* out = (float*)d_out;

    // Workspace layout (~64.6 MB):
    _Float16* hbuf = (_Float16*)d_ws;                      // N*D fp16 (25.6 MB)
    _Float16* act1 = hbuf + (size_t)N_NODES * D;           // N*D fp16 (25.6 MB)
    int2* ebuf     = (int2*)(act1 + (size_t)N_NODES * D);  // E int2 (12.8 MB), 8B-aligned
    int*  bcnt     = (int*)(ebuf + N_EDGES);               // NBUCK
    int*  boff     = bcnt + NBUCK;                         // NBUCK+1
    int*  gcur     = boff + (NBUCK + 1);                   // NBUCK
    int*  rowptr   = gcur + NBUCK;                         // N+1 ints (0.4 MB)
    char* Wt       = (char*)(rowptr + N_NODES + 8);        // 64 KB (two 32KB blobs)
    (void)ws_size; (void)in_sizes; (void)n_in; (void)out_size;

    // --- W prep (+bcnt zero) + CSR build (graph identical for both layers) ---
    k_wprep<<<33, 256, 0, stream>>>(W1, W2, Wt, bcnt);
    k_hist1<<<NWG1, 256, 0, stream>>>(edst, bcnt);
    k_scanN<<<1, 256, 0, stream>>>(bcnt, boff, gcur);
    k_scat1<<<NWG1, 256, 0, stream>>>(esrc, edst, ew, gcur, ebuf);
    k_sortb<<<NBUCK, 512, 0, stream>>>(ebuf, boff, rowptr);

    int gemm_blocks = (N_NODES + 63) / 64;                  // 1563
    int agg_blocks  = (N_NODES + 15) / 16;                  // 4 waves/block, 4 nodes/wave

    // --- layer 1 ---
    k_gemm<false><<<gemm_blocks, 256, 0, stream>>>(x, Wt, hbuf, N_NODES);
    k_agg<true><<<agg_blocks, 256, 0, stream>>>(hbuf, rowptr, ebuf, act1, N_NODES);
    // --- layer 2 ---
    k_gemm<true><<<gemm_blocks, 256, 0, stream>>>(act1, Wt + 32768, hbuf, N_NODES);
    k_agg<false><<<agg_blocks, 256, 0, stream>>>(hbuf, rowptr, ebuf, out, N_NODES);
}

// Round 17
// 222.539 us; speedup vs baseline: 1.0387x; 1.0359x over previous
//
#include <hip/hip_runtime.h>
#include <hip/hip_bf16.h>

#define N_NODES 100000
#define N_EDGES 1600000
#define D 128
#define BSZ 128                         // dst nodes per bucket
#define NBUCK 782                       // ceil(N_NODES / BSZ)
#define EPW 8192                        // edges per WG in hist/scatter
#define NWG1 ((N_EDGES + EPW - 1) / EPW)  // 196
#define CAP 4096                        // LDS edge staging per bucket (mean 2048)
#define OTS 272                         // epilogue LDS tile row stride (bytes)

typedef unsigned int  uint4n  __attribute__((ext_vector_type(4)));
typedef float         float4n __attribute__((ext_vector_type(4)));
typedef _Float16      half8n  __attribute__((ext_vector_type(8)));
typedef _Float16      half4n  __attribute__((ext_vector_type(4)));

// swizzled LDS byte offset for element (row, kb): 256B per row, XOR bits 4-7
#define SWZ(row, kb) (((row) << 8) + ((kb) ^ (((row) & 15) << 4)))

// tanh(x) = 1 - 2/(exp2(2*log2e*x)+1); hw exp2+rcp, abs err ~2e-7.
__device__ __forceinline__ float fast_tanh(float x) {
    float t = __builtin_amdgcn_exp2f(x * 2.885390081777927f);
    return 1.0f - 2.0f * __builtin_amdgcn_rcpf(t + 1.0f);
}

// ---------------- fused: W prep (blocks 0-31) || bucket histogram (blocks 32+) ----------------
// Element W[k][c] lands at byte SWZ(c, 2k) of its 32KB blob. bcnt pre-zeroed by memset.
__global__ __launch_bounds__(256) void k_wprep_hist(const float* __restrict__ W1,
                                                    const float* __restrict__ W2,
                                                    char* __restrict__ Wt,
                                                    const int* __restrict__ dst,
                                                    int* __restrict__ bcnt) {
    if (blockIdx.x < 32) {
        const float* W = (blockIdx.x < 16) ? W1 : W2;
        char* dstp = Wt + ((blockIdx.x < 16) ? 0 : 32768);
        int t = (blockIdx.x & 15) * 256 + threadIdx.x;   // 0..4095
        int idx = t * 4;
        int k = idx >> 7, c = idx & 127;
        float4 wv = *(const float4*)&W[idx];
        *(_Float16*)(dstp + SWZ(c + 0, k * 2)) = (_Float16)wv.x;
        *(_Float16*)(dstp + SWZ(c + 1, k * 2)) = (_Float16)wv.y;
        *(_Float16*)(dstp + SWZ(c + 2, k * 2)) = (_Float16)wv.z;
        *(_Float16*)(dstp + SWZ(c + 3, k * 2)) = (_Float16)wv.w;
        return;
    }
    __shared__ int h[NBUCK];
    for (int i = threadIdx.x; i < NBUCK; i += 256) h[i] = 0;
    __syncthreads();
    int hb   = blockIdx.x - 32;
    int base = hb * EPW;
    int end  = min(base + EPW, N_EDGES);
    for (int i = base + threadIdx.x; i < end; i += 256)
        atomicAdd(&h[dst[i] >> 7], 1);
    __syncthreads();
    for (int i = threadIdx.x; i < NBUCK; i += 256)
        if (h[i]) atomicAdd(&bcnt[i], h[i]);
}

// Single-block exclusive scan over NBUCK counts -> boff & gcur.
__global__ void k_scanN(const int* __restrict__ bcnt, int* __restrict__ boff,
                        int* __restrict__ gcur) {
    __shared__ int tmp[256];
    int tid = threadIdx.x;
    int carry = 0;
    for (int c = 0; c < (NBUCK + 255) / 256; c++) {
        int i = c * 256 + tid;
        int v = (i < NBUCK) ? bcnt[i] : 0;
        tmp[tid] = v;
        __syncthreads();
        int run = v;
        for (int off = 1; off < 256; off <<= 1) {
            int t = (tid >= off) ? tmp[tid - off] : 0;
            __syncthreads();
            run += t;
            tmp[tid] = run;
            __syncthreads();
        }
        int excl = carry + run - v;
        if (i < NBUCK) { boff[i] = excl; gcur[i] = excl; }
        int tot = tmp[255];
        __syncthreads();
        carry += tot;
    }
    if (tid == 0) boff[NBUCK] = N_EDGES;
}

// ---------------- fused: bucket scatter (blocks 0-195) || GEMM layer 1 (blocks 196+) ----------
// Scatter payload: (src<<8 | dst&127, weight) = 8B; src<<8 IS the byte offset of H row.
// GEMM: H[n x 128](fp16) = X_f32 @ W1, staged fp16 LDS, MFMA 16x16x32.
__global__ __launch_bounds__(256) void k_scat_gemm(const int* __restrict__ src,
                                                   const int* __restrict__ dst,
                                                   const float* __restrict__ ew,
                                                   int* __restrict__ gcur,
                                                   int2* __restrict__ ebuf,
                                                   const float* __restrict__ Xf,
                                                   const char* __restrict__ Wt,
                                                   _Float16* __restrict__ H, int n) {
    __shared__ char smem[17408];
    int tid = threadIdx.x;

    if (blockIdx.x < NWG1) {
        // ---- scatter role ----
        int* h  = (int*)smem;
        int* rb = h + NBUCK;
        for (int i = tid; i < NBUCK; i += 256) h[i] = 0;
        __syncthreads();
        int base = blockIdx.x * EPW;
        int end  = min(base + EPW, N_EDGES);
        for (int i = base + tid; i < end; i += 256)
            atomicAdd(&h[dst[i] >> 7], 1);
        __syncthreads();
        for (int i = tid; i < NBUCK; i += 256) {
            int c = h[i];
            if (c) rb[i] = atomicAdd(&gcur[i], c);   // reserve contiguous range
        }
        __syncthreads();
        for (int i = base + tid; i < end; i += 256) {
            int d  = dst[i];
            int bk = d >> 7;
            int p  = atomicAdd(&rb[bk], 1);          // LDS int cursor
            ebuf[p] = make_int2((src[i] << 8) | (d & 127), __float_as_int(ew[i]));
        }
        return;
    }

    // ---- GEMM layer-1 role ----
    char* sA = smem;
    int lane = tid & 63, w = tid >> 6;
    int rows0 = (blockIdx.x - NWG1) * 64;

    int rb2 = (w >> 1) * 32;     // wave row base within slab (0/32)
    int cb = (w & 1) * 64;       // wave col base (0/64)
    int lr = lane & 15;          // frag row/col within tile
    int kg = (lane >> 4) * 16;   // k-group byte offset

    #pragma unroll
    for (int rep = 0; rep < 8; rep++) {
        int ef = rep * 1024 + tid * 4;
        int r = ef >> 7, c = ef & 127;
        int rg = rows0 + r;
        float4 xv = make_float4(0.f, 0.f, 0.f, 0.f);
        if (rg < n) xv = *(const float4*)(Xf + (size_t)rg * 128 + c);
        half4n hv;
        hv[0] = (_Float16)xv.x; hv[1] = (_Float16)xv.y;
        hv[2] = (_Float16)xv.z; hv[3] = (_Float16)xv.w;
        *(half4n*)(sA + SWZ(r, c * 2)) = hv;
    }
    __syncthreads();

    float4n acc[2][4] = {};
    #pragma unroll
    for (int ks = 0; ks < 4; ks++) {
        half8n bwk[4];
        #pragma unroll
        for (int ct = 0; ct < 4; ct++)
            bwk[ct] = *(const half8n*)(Wt + SWZ(cb + ct * 16 + lr, ks * 64 + kg));
        half8n af[2];
        #pragma unroll
        for (int rt = 0; rt < 2; rt++)
            af[rt] = *(const half8n*)(sA + SWZ(rb2 + rt * 16 + lr, ks * 64 + kg));
        #pragma unroll
        for (int rt = 0; rt < 2; rt++)
            #pragma unroll
            for (int ct = 0; ct < 4; ct++)
                acc[rt][ct] = __builtin_amdgcn_mfma_f32_16x16x32_f16(af[rt], bwk[ct], acc[rt][ct], 0, 0, 0);
    }

    __syncthreads();                              // sA dead, reuse as OT
    char* OT = smem;
    int rloc = rb2 + (lane >> 4) * 4;
    #pragma unroll
    for (int rt = 0; rt < 2; rt++) {
        #pragma unroll
        for (int ct = 0; ct < 4; ct++) {
            int col = cb + ct * 16 + lr;
            #pragma unroll
            for (int r = 0; r < 4; r++)
                *(_Float16*)(OT + (rloc + rt * 16 + r) * OTS + col * 2) = (_Float16)acc[rt][ct][r];
        }
    }
    __syncthreads();
    #pragma unroll
    for (int rep = 0; rep < 4; rep++) {
        int ef = rep * 2048 + tid * 8;
        int r = ef >> 7, c = ef & 127;
        int rg = rows0 + r;
        if (rg < n) {
            half8n v = *(const half8n*)(OT + r * OTS + c * 2);
            *(half8n*)&H[(size_t)rg * 128 + c] = v;
        }
    }
}

// ---------------- stage 2: per-bucket counting sort (in-place via LDS) + rowptr ----------------
__global__ __launch_bounds__(512) void k_sortb(int2* __restrict__ ebuf,
                                               const int* __restrict__ boff,
                                               int* __restrict__ rowptr) {
    __shared__ int2 se[CAP];
    __shared__ int cnt[BSZ];
    __shared__ int cur[BSZ];
    int tid = threadIdx.x;
    int b   = blockIdx.x;
    int e0 = boff[b], e1 = boff[b + 1];
    int m  = e1 - e0;
    if (tid < BSZ) cnt[tid] = 0;
    __syncthreads();
    int2 ovf;
    bool hasOvf = false;
    for (int i = tid; i < m; i += 512) {          // all GLOBAL reads happen here
        int2 v = ebuf[e0 + i];
        if (i < CAP) se[i] = v;
        else { ovf = v; hasOvf = true; }          // statistically never (m~2048±45)
        atomicAdd(&cnt[v.x & (BSZ - 1)], 1);
    }
    __syncthreads();
    if (tid < 64) {                               // wave-0 shfl scan of 128 counts
        int a  = cnt[tid * 2], bq = cnt[tid * 2 + 1];
        int s  = a + bq;
        int incl = s;
        #pragma unroll
        for (int off = 1; off < 64; off <<= 1) {
            int t = __shfl_up(incl, off, 64);
            if (tid >= off) incl += t;
        }
        int ex = incl - s;                        // exclusive prefix of this pair
        cur[tid * 2]     = ex;
        cur[tid * 2 + 1] = ex + a;
        int node = b * BSZ + tid * 2;
        if (node     <= N_NODES) rowptr[node]     = e0 + ex;
        if (node + 1 <= N_NODES) rowptr[node + 1] = e0 + ex + a;
    }
    __syncthreads();
    for (int i = tid; i < m && i < CAP; i += 512) {
        int2 v = se[i];
        int p = atomicAdd(&cur[v.x & (BSZ - 1)], 1);
        ebuf[e0 + p] = v;
    }
    if (hasOvf) {
        int p = atomicAdd(&cur[ovf.x & (BSZ - 1)], 1);
        ebuf[e0 + p] = ovf;
    }
}

// ---------------- GEMM (layer 2, fp16 in): staged LDS path ----------------
__global__ __launch_bounds__(256) void k_gemm2(const _Float16* __restrict__ Xh,
                                               const char* __restrict__ Wt,
                                               _Float16* __restrict__ H, int n) {
    __shared__ char smem[17408];
    char* sA = smem;
    int tid  = threadIdx.x;
    int lane = tid & 63, w = tid >> 6;
    int rows0 = blockIdx.x * 64;

    int rb = (w >> 1) * 32;
    int cb = (w & 1) * 64;
    int lr = lane & 15;
    int kg = (lane >> 4) * 16;

    #pragma unroll
    for (int rep = 0; rep < 4; rep++) {
        int ef = rep * 2048 + tid * 8;
        int r = ef >> 7, c = ef & 127;
        int rg = rows0 + r;
        half8n v = half8n(0);
        if (rg < n) v = *(const half8n*)(Xh + (size_t)rg * 128 + c);
        *(half8n*)(sA + SWZ(r, c * 2)) = v;
    }
    __syncthreads();

    float4n acc[2][4] = {};
    #pragma unroll
    for (int ks = 0; ks < 4; ks++) {
        half8n bwk[4];
        #pragma unroll
        for (int ct = 0; ct < 4; ct++)
            bwk[ct] = *(const half8n*)(Wt + SWZ(cb + ct * 16 + lr, ks * 64 + kg));
        half8n af[2];
        #pragma unroll
        for (int rt = 0; rt < 2; rt++)
            af[rt] = *(const half8n*)(sA + SWZ(rb + rt * 16 + lr, ks * 64 + kg));
        #pragma unroll
        for (int rt = 0; rt < 2; rt++)
            #pragma unroll
            for (int ct = 0; ct < 4; ct++)
                acc[rt][ct] = __builtin_amdgcn_mfma_f32_16x16x32_f16(af[rt], bwk[ct], acc[rt][ct], 0, 0, 0);
    }

    __syncthreads();
    char* OT = smem;
    int rloc = rb + (lane >> 4) * 4;
    #pragma unroll
    for (int rt = 0; rt < 2; rt++) {
        #pragma unroll
        for (int ct = 0; ct < 4; ct++) {
            int col = cb + ct * 16 + lr;
            #pragma unroll
            for (int r = 0; r < 4; r++)
                *(_Float16*)(OT + (rloc + rt * 16 + r) * OTS + col * 2) = (_Float16)acc[rt][ct][r];
        }
    }
    __syncthreads();
    #pragma unroll
    for (int rep = 0; rep < 4; rep++) {
        int ef = rep * 2048 + tid * 8;
        int r = ef >> 7, c = ef & 127;
        int rg = rows0 + r;
        if (rg < n) {
            half8n v = *(const half8n*)(OT + r * OTS + c * 2);
            *(half8n*)&H[(size_t)rg * 128 + c] = v;
        }
    }
}

// ---------------- Aggregation: out[n] = tanh(sum_e w_e * H[src_e]) ----------------
// FOUR nodes per wave (16-lane group per node). Inner loop keeps FOUR gathers
// in flight: load 4 edge records first, then issue 4 H-row gathers, then FMAs.
template<bool OUTF16>
__global__ __launch_bounds__(256) void k_agg(const _Float16* __restrict__ H,
                                             const int* __restrict__ rowptr,
                                             const int2* __restrict__ ebuf,
                                             void* __restrict__ outv, int n) {
    int wv   = (blockIdx.x * 256 + threadIdx.x) >> 6;   // global wave index
    int lane = threadIdx.x & 63;
    int g = lane >> 4;                 // node slot within wave (0..3)
    int c = lane & 15;                 // columns c*8 .. c*8+7 (16B of the row)
    int node = wv * 4 + g;
    if (node >= n) return;
    const char* Hc = (const char*)H + (c << 4);   // per-lane column base
    int e0 = rowptr[node], e1 = rowptr[node + 1];
    float acc[8] = {};
    int e = e0;
    for (; e + 4 <= e1; e += 4) {                 // 4 gathers in flight
        int2 d0 = ebuf[e];
        int2 d1 = ebuf[e + 1];
        int2 d2 = ebuf[e + 2];
        int2 d3 = ebuf[e + 3];
        half8n v0 = *(const half8n*)(Hc + (size_t)((unsigned)d0.x & 0xFFFFFF00u));
        half8n v1 = *(const half8n*)(Hc + (size_t)((unsigned)d1.x & 0xFFFFFF00u));
        half8n v2 = *(const half8n*)(Hc + (size_t)((unsigned)d2.x & 0xFFFFFF00u));
        half8n v3 = *(const half8n*)(Hc + (size_t)((unsigned)d3.x & 0xFFFFFF00u));
        float w0 = __int_as_float(d0.y);
        float w1 = __int_as_float(d1.y);
        float w2 = __int_as_float(d2.y);
        float w3 = __int_as_float(d3.y);
        #pragma unroll
        for (int j = 0; j < 8; j++) acc[j] = __builtin_fmaf((float)v0[j], w0, acc[j]);
        #pragma unroll
        for (int j = 0; j < 8; j++) acc[j] = __builtin_fmaf((float)v1[j], w1, acc[j]);
        #pragma unroll
        for (int j = 0; j < 8; j++) acc[j] = __builtin_fmaf((float)v2[j], w2, acc[j]);
        #pragma unroll
        for (int j = 0; j < 8; j++) acc[j] = __builtin_fmaf((float)v3[j], w3, acc[j]);
    }
    for (; e < e1; ++e) {
        int2 ed = ebuf[e];
        half8n v = *(const half8n*)(Hc + (size_t)((unsigned)ed.x & 0xFFFFFF00u));
        float w = __int_as_float(ed.y);
        #pragma unroll
        for (int j = 0; j < 8; j++) acc[j] = __builtin_fmaf((float)v[j], w, acc[j]);
    }
    if (OUTF16) {
        half8n hv;
        #pragma unroll
        for (int j = 0; j < 8; j++) hv[j] = (_Float16)fast_tanh(acc[j]);
        // plain store: act1 is re-read by the next GEMM, keep it cache-resident
        *(uint4n*)((_Float16*)outv + (size_t)node * 128 + c * 8) = *(uint4n*)&hv;
    } else {
        float* op = (float*)outv + (size_t)node * 128 + c * 8;
        float4n o0, o1;
        o0.x = fast_tanh(acc[0]); o0.y = fast_tanh(acc[1]);
        o0.z = fast_tanh(acc[2]); o0.w = fast_tanh(acc[3]);
        o1.x = fast_tanh(acc[4]); o1.y = fast_tanh(acc[5]);
        o1.z = fast_tanh(acc[6]); o1.w = fast_tanh(acc[7]);
        __builtin_nontemporal_store(o0, (float4n*)op);
        __builtin_nontemporal_store(o1, (float4n*)(op + 4));
    }
}

// ---------------- launch ----------------

extern "C" void kernel_launch(void* const* d_in, const int* in_sizes, int n_in,
                              void* d_out, int out_size, void* d_ws, size_t ws_size,
                              hipStream_t stream) {
    const float* x    = (const float*)d_in[0];
    const int*   esrc = (const int*)d_in[1];
    const int*   edst = (const int*)d_in[2];
    const float* ew   = (const float*)d_in[3];
    const float* W1   = (const float*)d_in[4];
    const float* W2   = (const float*)d_in[5];
    float* out = (float*)d_out;

    // Workspace layout (~64.6 MB):
    _Float16* hbuf = (_Float16*)d_ws;                      // N*D fp16 (25.6 MB)
    _Float16* act1 = hbuf + (size_t)N_NODES * D;           // N*D fp16 (25.6 MB)
    int2* ebuf     = (int2*)(act1 + (size_t)N_NODES * D);  // E int2 (12.8 MB), 8B-aligned
    int*  bcnt     = (int*)(ebuf + N_EDGES);               // NBUCK
    int*  boff     = bcnt + NBUCK;                         // NBUCK+1
    int*  gcur     = boff + (NBUCK + 1);                   // NBUCK
    int*  rowptr   = gcur + NBUCK;                         // N+1 ints (0.4 MB)
    char* Wt       = (char*)(rowptr + N_NODES + 8);        // 64 KB (two 32KB blobs)
    (void)ws_size; (void)in_sizes; (void)n_in; (void)out_size;

    int gemm_blocks = (N_NODES + 63) / 64;                  // 1563
    int agg_blocks  = (N_NODES + 15) / 16;                  // 4 waves/block, 4 nodes/wave

    // --- CSR build overlapped with W prep and GEMM-1 ---
    hipMemsetAsync(bcnt, 0, NBUCK * sizeof(int), stream);
    k_wprep_hist<<<32 + NWG1, 256, 0, stream>>>(W1, W2, Wt, edst, bcnt);
    k_scanN<<<1, 256, 0, stream>>>(bcnt, boff, gcur);
    k_scat_gemm<<<NWG1 + gemm_blocks, 256, 0, stream>>>(esrc, edst, ew, gcur, ebuf,
                                                        x, Wt, hbuf, N_NODES);
    k_sortb<<<NBUCK, 512, 0, stream>>>(ebuf, boff, rowptr);

    // --- layer 1 aggregation ---
    k_agg<true><<<agg_blocks, 256, 0, stream>>>(hbuf, rowptr, ebuf, act1, N_NODES);
    // --- layer 2 ---
    k_gemm2<<<gemm_blocks, 256, 0, stream>>>(act1, Wt + 32768, hbuf, N_NODES);
    k_agg<false><<<agg_blocks, 256, 0, stream>>>(hbuf, rowptr, ebuf, out, N_NODES);
}

// Round 18
// 219.252 us; speedup vs baseline: 1.0543x; 1.0150x over previous
//
#include <hip/hip_runtime.h>
#include <hip/hip_bf16.h>

#define N_NODES 100000
#define N_EDGES 1600000
#define D 128
#define BSZ 128                         // dst nodes per bucket
#define NBUCK 782                       // ceil(N_NODES / BSZ)
#define EPW 4096                        // edges per WG in hist/scatter
#define NWG1 ((N_EDGES + EPW - 1) / EPW)  // 391
#define CAP 4096                        // LDS edge staging per bucket (mean 2048)
#define OTS 272                         // epilogue LDS tile row stride (bytes)

typedef unsigned int  uint4n  __attribute__((ext_vector_type(4)));
typedef float         float4n __attribute__((ext_vector_type(4)));
typedef _Float16      half8n  __attribute__((ext_vector_type(8)));
typedef _Float16      half4n  __attribute__((ext_vector_type(4)));

// swizzled LDS byte offset for element (row, kb): 256B per row, XOR bits 4-7
#define SWZ(row, kb) (((row) << 8) + ((kb) ^ (((row) & 15) << 4)))

// tanh(x) = 1 - 2/(exp2(2*log2e*x)+1); hw exp2+rcp, abs err ~2e-7.
__device__ __forceinline__ float fast_tanh(float x) {
    float t = __builtin_amdgcn_exp2f(x * 2.885390081777927f);
    return 1.0f - 2.0f * __builtin_amdgcn_rcpf(t + 1.0f);
}

// ---------------- fused: W prep (blocks 0-31) || bucket histogram (blocks 32+) ----------------
// Element W[k][c] lands at byte SWZ(c, 2k) of its 32KB blob. bcnt pre-zeroed by memset.
__global__ __launch_bounds__(256) void k_wprep_hist(const float* __restrict__ W1,
                                                    const float* __restrict__ W2,
                                                    char* __restrict__ Wt,
                                                    const int* __restrict__ dst,
                                                    int* __restrict__ bcnt) {
    if (blockIdx.x < 32) {
        const float* W = (blockIdx.x < 16) ? W1 : W2;
        char* dstp = Wt + ((blockIdx.x < 16) ? 0 : 32768);
        int t = (blockIdx.x & 15) * 256 + threadIdx.x;   // 0..4095
        int idx = t * 4;
        int k = idx >> 7, c = idx & 127;
        float4 wv = *(const float4*)&W[idx];
        *(_Float16*)(dstp + SWZ(c + 0, k * 2)) = (_Float16)wv.x;
        *(_Float16*)(dstp + SWZ(c + 1, k * 2)) = (_Float16)wv.y;
        *(_Float16*)(dstp + SWZ(c + 2, k * 2)) = (_Float16)wv.z;
        *(_Float16*)(dstp + SWZ(c + 3, k * 2)) = (_Float16)wv.w;
        return;
    }
    __shared__ int h[NBUCK];
    for (int i = threadIdx.x; i < NBUCK; i += 256) h[i] = 0;
    __syncthreads();
    int hb   = blockIdx.x - 32;
    int base = hb * EPW;
    int end  = min(base + EPW, N_EDGES);
    int i = base + threadIdx.x;
    for (; i + 768 < end; i += 1024) {            // 4 loads in flight
        int d0 = dst[i], d1 = dst[i + 256], d2 = dst[i + 512], d3 = dst[i + 768];
        atomicAdd(&h[d0 >> 7], 1);
        atomicAdd(&h[d1 >> 7], 1);
        atomicAdd(&h[d2 >> 7], 1);
        atomicAdd(&h[d3 >> 7], 1);
    }
    for (; i < end; i += 256)
        atomicAdd(&h[dst[i] >> 7], 1);
    __syncthreads();
    for (int j = threadIdx.x; j < NBUCK; j += 256)
        if (h[j]) atomicAdd(&bcnt[j], h[j]);
}

// Single-block exclusive scan over NBUCK counts -> boff & gcur.
__global__ void k_scanN(const int* __restrict__ bcnt, int* __restrict__ boff,
                        int* __restrict__ gcur) {
    __shared__ int tmp[256];
    int tid = threadIdx.x;
    int carry = 0;
    for (int c = 0; c < (NBUCK + 255) / 256; c++) {
        int i = c * 256 + tid;
        int v = (i < NBUCK) ? bcnt[i] : 0;
        tmp[tid] = v;
        __syncthreads();
        int run = v;
        for (int off = 1; off < 256; off <<= 1) {
            int t = (tid >= off) ? tmp[tid - off] : 0;
            __syncthreads();
            run += t;
            tmp[tid] = run;
            __syncthreads();
        }
        int excl = carry + run - v;
        if (i < NBUCK) { boff[i] = excl; gcur[i] = excl; }
        int tot = tmp[255];
        __syncthreads();
        carry += tot;
    }
    if (tid == 0) boff[NBUCK] = N_EDGES;
}

// ---------------- fused: bucket scatter (blocks 0..NWG1-1) || GEMM layer 1 ----------
// Scatter payload: (src<<8 | dst&127, weight) = 8B; src<<8 IS the byte offset of H row.
// Scatter: 4-deep unrolled batched loads + independent LDS-cursor atomics (MLP 4).
// GEMM: H[n x 128](fp16) = X_f32 @ W1, staged fp16 LDS, MFMA 16x16x32.
__global__ __launch_bounds__(256) void k_scat_gemm(const int* __restrict__ src,
                                                   const int* __restrict__ dst,
                                                   const float* __restrict__ ew,
                                                   int* __restrict__ gcur,
                                                   int2* __restrict__ ebuf,
                                                   const float* __restrict__ Xf,
                                                   const char* __restrict__ Wt,
                                                   _Float16* __restrict__ H, int n) {
    __shared__ char smem[17408];
    int tid = threadIdx.x;

    if (blockIdx.x < NWG1) {
        // ---- scatter role ----
        int* h  = (int*)smem;
        int* rb = h + NBUCK;
        for (int i = tid; i < NBUCK; i += 256) h[i] = 0;
        __syncthreads();
        int base = blockIdx.x * EPW;
        int end  = min(base + EPW, N_EDGES);
        {
            int i = base + tid;
            for (; i + 768 < end; i += 1024) {     // 4 loads in flight
                int d0 = dst[i], d1 = dst[i + 256], d2 = dst[i + 512], d3 = dst[i + 768];
                atomicAdd(&h[d0 >> 7], 1);
                atomicAdd(&h[d1 >> 7], 1);
                atomicAdd(&h[d2 >> 7], 1);
                atomicAdd(&h[d3 >> 7], 1);
            }
            for (; i < end; i += 256)
                atomicAdd(&h[dst[i] >> 7], 1);
        }
        __syncthreads();
        for (int i = tid; i < NBUCK; i += 256) {
            int c = h[i];
            if (c) rb[i] = atomicAdd(&gcur[i], c);   // reserve contiguous range
        }
        __syncthreads();
        {
            int i = base + tid;
            for (; i + 768 < end; i += 1024) {     // batched loads, 4 indep chains
                int d0 = dst[i], d1 = dst[i + 256], d2 = dst[i + 512], d3 = dst[i + 768];
                int s0 = src[i], s1 = src[i + 256], s2 = src[i + 512], s3 = src[i + 768];
                float w0 = ew[i], w1 = ew[i + 256], w2 = ew[i + 512], w3 = ew[i + 768];
                int p0 = atomicAdd(&rb[d0 >> 7], 1);
                int p1 = atomicAdd(&rb[d1 >> 7], 1);
                int p2 = atomicAdd(&rb[d2 >> 7], 1);
                int p3 = atomicAdd(&rb[d3 >> 7], 1);
                ebuf[p0] = make_int2((s0 << 8) | (d0 & 127), __float_as_int(w0));
                ebuf[p1] = make_int2((s1 << 8) | (d1 & 127), __float_as_int(w1));
                ebuf[p2] = make_int2((s2 << 8) | (d2 & 127), __float_as_int(w2));
                ebuf[p3] = make_int2((s3 << 8) | (d3 & 127), __float_as_int(w3));
            }
            for (; i < end; i += 256) {
                int d = dst[i];
                int p = atomicAdd(&rb[d >> 7], 1);
                ebuf[p] = make_int2((src[i] << 8) | (d & 127), __float_as_int(ew[i]));
            }
        }
        return;
    }

    // ---- GEMM layer-1 role ----
    char* sA = smem;
    int lane = tid & 63, w = tid >> 6;
    int rows0 = (blockIdx.x - NWG1) * 64;

    int rb2 = (w >> 1) * 32;     // wave row base within slab (0/32)
    int cb = (w & 1) * 64;       // wave col base (0/64)
    int lr = lane & 15;          // frag row/col within tile
    int kg = (lane >> 4) * 16;   // k-group byte offset

    #pragma unroll
    for (int rep = 0; rep < 8; rep++) {
        int ef = rep * 1024 + tid * 4;
        int r = ef >> 7, c = ef & 127;
        int rg = rows0 + r;
        float4 xv = make_float4(0.f, 0.f, 0.f, 0.f);
        if (rg < n) xv = *(const float4*)(Xf + (size_t)rg * 128 + c);
        half4n hv;
        hv[0] = (_Float16)xv.x; hv[1] = (_Float16)xv.y;
        hv[2] = (_Float16)xv.z; hv[3] = (_Float16)xv.w;
        *(half4n*)(sA + SWZ(r, c * 2)) = hv;
    }
    __syncthreads();

    float4n acc[2][4] = {};
    #pragma unroll
    for (int ks = 0; ks < 4; ks++) {
        half8n bwk[4];
        #pragma unroll
        for (int ct = 0; ct < 4; ct++)
            bwk[ct] = *(const half8n*)(Wt + SWZ(cb + ct * 16 + lr, ks * 64 + kg));
        half8n af[2];
        #pragma unroll
        for (int rt = 0; rt < 2; rt++)
            af[rt] = *(const half8n*)(sA + SWZ(rb2 + rt * 16 + lr, ks * 64 + kg));
        #pragma unroll
        for (int rt = 0; rt < 2; rt++)
            #pragma unroll
            for (int ct = 0; ct < 4; ct++)
                acc[rt][ct] = __builtin_amdgcn_mfma_f32_16x16x32_f16(af[rt], bwk[ct], acc[rt][ct], 0, 0, 0);
    }

    __syncthreads();                              // sA dead, reuse as OT
    char* OT = smem;
    int rloc = rb2 + (lane >> 4) * 4;
    #pragma unroll
    for (int rt = 0; rt < 2; rt++) {
        #pragma unroll
        for (int ct = 0; ct < 4; ct++) {
            int col = cb + ct * 16 + lr;
            #pragma unroll
            for (int r = 0; r < 4; r++)
                *(_Float16*)(OT + (rloc + rt * 16 + r) * OTS + col * 2) = (_Float16)acc[rt][ct][r];
        }
    }
    __syncthreads();
    #pragma unroll
    for (int rep = 0; rep < 4; rep++) {
        int ef = rep * 2048 + tid * 8;
        int r = ef >> 7, c = ef & 127;
        int rg = rows0 + r;
        if (rg < n) {
            half8n v = *(const half8n*)(OT + r * OTS + c * 2);
            *(half8n*)&H[(size_t)rg * 128 + c] = v;
        }
    }
}

// ---------------- stage 2: per-bucket counting sort (in-place via LDS) + rowptr ----------------
__global__ __launch_bounds__(512) void k_sortb(int2* __restrict__ ebuf,
                                               const int* __restrict__ boff,
                                               int* __restrict__ rowptr) {
    __shared__ int2 se[CAP];
    __shared__ int cnt[BSZ];
    __shared__ int cur[BSZ];
    int tid = threadIdx.x;
    int b   = blockIdx.x;
    int e0 = boff[b], e1 = boff[b + 1];
    int m  = e1 - e0;
    if (tid < BSZ) cnt[tid] = 0;
    __syncthreads();
    int2 ovf;
    bool hasOvf = false;
    for (int i = tid; i < m; i += 512) {          // all GLOBAL reads happen here
        int2 v = ebuf[e0 + i];
        if (i < CAP) se[i] = v;
        else { ovf = v; hasOvf = true; }          // statistically never (m~2048±45)
        atomicAdd(&cnt[v.x & (BSZ - 1)], 1);
    }
    __syncthreads();
    if (tid < 64) {                               // wave-0 shfl scan of 128 counts
        int a  = cnt[tid * 2], bq = cnt[tid * 2 + 1];
        int s  = a + bq;
        int incl = s;
        #pragma unroll
        for (int off = 1; off < 64; off <<= 1) {
            int t = __shfl_up(incl, off, 64);
            if (tid >= off) incl += t;
        }
        int ex = incl - s;                        // exclusive prefix of this pair
        cur[tid * 2]     = ex;
        cur[tid * 2 + 1] = ex + a;
        int node = b * BSZ + tid * 2;
        if (node     <= N_NODES) rowptr[node]     = e0 + ex;
        if (node + 1 <= N_NODES) rowptr[node + 1] = e0 + ex + a;
    }
    __syncthreads();
    for (int i = tid; i < m && i < CAP; i += 512) {
        int2 v = se[i];
        int p = atomicAdd(&cur[v.x & (BSZ - 1)], 1);
        ebuf[e0 + p] = v;
    }
    if (hasOvf) {
        int p = atomicAdd(&cur[ovf.x & (BSZ - 1)], 1);
        ebuf[e0 + p] = ovf;
    }
}

// ---------------- GEMM (layer 2, fp16 in): staged LDS path ----------------
__global__ __launch_bounds__(256) void k_gemm2(const _Float16* __restrict__ Xh,
                                               const char* __restrict__ Wt,
                                               _Float16* __restrict__ H, int n) {
    __shared__ char smem[17408];
    char* sA = smem;
    int tid  = threadIdx.x;
    int lane = tid & 63, w = tid >> 6;
    int rows0 = blockIdx.x * 64;

    int rb = (w >> 1) * 32;
    int cb = (w & 1) * 64;
    int lr = lane & 15;
    int kg = (lane >> 4) * 16;

    #pragma unroll
    for (int rep = 0; rep < 4; rep++) {
        int ef = rep * 2048 + tid * 8;
        int r = ef >> 7, c = ef & 127;
        int rg = rows0 + r;
        half8n v = half8n(0);
        if (rg < n) v = *(const half8n*)(Xh + (size_t)rg * 128 + c);
        *(half8n*)(sA + SWZ(r, c * 2)) = v;
    }
    __syncthreads();

    float4n acc[2][4] = {};
    #pragma unroll
    for (int ks = 0; ks < 4; ks++) {
        half8n bwk[4];
        #pragma unroll
        for (int ct = 0; ct < 4; ct++)
            bwk[ct] = *(const half8n*)(Wt + SWZ(cb + ct * 16 + lr, ks * 64 + kg));
        half8n af[2];
        #pragma unroll
        for (int rt = 0; rt < 2; rt++)
            af[rt] = *(const half8n*)(sA + SWZ(rb + rt * 16 + lr, ks * 64 + kg));
        #pragma unroll
        for (int rt = 0; rt < 2; rt++)
            #pragma unroll
            for (int ct = 0; ct < 4; ct++)
                acc[rt][ct] = __builtin_amdgcn_mfma_f32_16x16x32_f16(af[rt], bwk[ct], acc[rt][ct], 0, 0, 0);
    }

    __syncthreads();
    char* OT = smem;
    int rloc = rb + (lane >> 4) * 4;
    #pragma unroll
    for (int rt = 0; rt < 2; rt++) {
        #pragma unroll
        for (int ct = 0; ct < 4; ct++) {
            int col = cb + ct * 16 + lr;
            #pragma unroll
            for (int r = 0; r < 4; r++)
                *(_Float16*)(OT + (rloc + rt * 16 + r) * OTS + col * 2) = (_Float16)acc[rt][ct][r];
        }
    }
    __syncthreads();
    #pragma unroll
    for (int rep = 0; rep < 4; rep++) {
        int ef = rep * 2048 + tid * 8;
        int r = ef >> 7, c = ef & 127;
        int rg = rows0 + r;
        if (rg < n) {
            half8n v = *(const half8n*)(OT + r * OTS + c * 2);
            *(half8n*)&H[(size_t)rg * 128 + c] = v;
        }
    }
}

// ---------------- Aggregation: out[n] = tanh(sum_e w_e * H[src_e]) ----------------
// FOUR nodes per wave (16-lane group per node). Inner loop keeps FOUR gathers
// in flight: load 4 edge records first, then issue 4 H-row gathers, then FMAs.
template<bool OUTF16>
__global__ __launch_bounds__(256) void k_agg(const _Float16* __restrict__ H,
                                             const int* __restrict__ rowptr,
                                             const int2* __restrict__ ebuf,
                                             void* __restrict__ outv, int n) {
    int wv   = (blockIdx.x * 256 + threadIdx.x) >> 6;   // global wave index
    int lane = threadIdx.x & 63;
    int g = lane >> 4;                 // node slot within wave (0..3)
    int c = lane & 15;                 // columns c*8 .. c*8+7 (16B of the row)
    int node = wv * 4 + g;
    if (node >= n) return;
    const char* Hc = (const char*)H + (c << 4);   // per-lane column base
    int e0 = rowptr[node], e1 = rowptr[node + 1];
    float acc[8] = {};
    int e = e0;
    for (; e + 4 <= e1; e += 4) {                 // 4 gathers in flight
        int2 d0 = ebuf[e];
        int2 d1 = ebuf[e + 1];
        int2 d2 = ebuf[e + 2];
        int2 d3 = ebuf[e + 3];
        half8n v0 = *(const half8n*)(Hc + (size_t)((unsigned)d0.x & 0xFFFFFF00u));
        half8n v1 = *(const half8n*)(Hc + (size_t)((unsigned)d1.x & 0xFFFFFF00u));
        half8n v2 = *(const half8n*)(Hc + (size_t)((unsigned)d2.x & 0xFFFFFF00u));
        half8n v3 = *(const half8n*)(Hc + (size_t)((unsigned)d3.x & 0xFFFFFF00u));
        float w0 = __int_as_float(d0.y);
        float w1 = __int_as_float(d1.y);
        float w2 = __int_as_float(d2.y);
        float w3 = __int_as_float(d3.y);
        #pragma unroll
        for (int j = 0; j < 8; j++) acc[j] = __builtin_fmaf((float)v0[j], w0, acc[j]);
        #pragma unroll
        for (int j = 0; j < 8; j++) acc[j] = __builtin_fmaf((float)v1[j], w1, acc[j]);
        #pragma unroll
        for (int j = 0; j < 8; j++) acc[j] = __builtin_fmaf((float)v2[j], w2, acc[j]);
        #pragma unroll
        for (int j = 0; j < 8; j++) acc[j] = __builtin_fmaf((float)v3[j], w3, acc[j]);
    }
    for (; e < e1; ++e) {
        int2 ed = ebuf[e];
        half8n v = *(const half8n*)(Hc + (size_t)((unsigned)ed.x & 0xFFFFFF00u));
        float w = __int_as_float(ed.y);
        #pragma unroll
        for (int j = 0; j < 8; j++) acc[j] = __builtin_fmaf((float)v[j], w, acc[j]);
    }
    if (OUTF16) {
        half8n hv;
        #pragma unroll
        for (int j = 0; j < 8; j++) hv[j] = (_Float16)fast_tanh(acc[j]);
        // plain store: act1 is re-read by the next GEMM, keep it cache-resident
        *(uint4n*)((_Float16*)outv + (size_t)node * 128 + c * 8) = *(uint4n*)&hv;
    } else {
        float* op = (float*)outv + (size_t)node * 128 + c * 8;
        float4n o0, o1;
        o0.x = fast_tanh(acc[0]); o0.y = fast_tanh(acc[1]);
        o0.z = fast_tanh(acc[2]); o0.w = fast_tanh(acc[3]);
        o1.x = fast_tanh(acc[4]); o1.y = fast_tanh(acc[5]);
        o1.z = fast_tanh(acc[6]); o1.w = fast_tanh(acc[7]);
        __builtin_nontemporal_store(o0, (float4n*)op);
        __builtin_nontemporal_store(o1, (float4n*)(op + 4));
    }
}

// ---------------- launch ----------------

extern "C" void kernel_launch(void* const* d_in, const int* in_sizes, int n_in,
                              void* d_out, int out_size, void* d_ws, size_t ws_size,
                              hipStream_t stream) {
    const float* x    = (const float*)d_in[0];
    const int*   esrc = (const int*)d_in[1];
    const int*   edst = (const int*)d_in[2];
    const float* ew   = (const float*)d_in[3];
    const float* W1   = (const float*)d_in[4];
    const float* W2   = (const float*)d_in[5];
    float* out = (float*)d_out;

    // Workspace layout (~64.6 MB):
    _Float16* hbuf = (_Float16*)d_ws;                      // N*D fp16 (25.6 MB)
    _Float16* act1 = hbuf + (size_t)N_NODES * D;           // N*D fp16 (25.6 MB)
    int2* ebuf     = (int2*)(act1 + (size_t)N_NODES * D);  // E int2 (12.8 MB), 8B-aligned
    int*  bcnt     = (int*)(ebuf + N_EDGES);               // NBUCK
    int*  boff     = bcnt + NBUCK;                         // NBUCK+1
    int*  gcur     = boff + (NBUCK + 1);                   // NBUCK
    int*  rowptr   = gcur + NBUCK;                         // N+1 ints (0.4 MB)
    char* Wt       = (char*)(rowptr + N_NODES + 8);        // 64 KB (two 32KB blobs)
    (void)ws_size; (void)in_sizes; (void)n_in; (void)out_size;

    int gemm_blocks = (N_NODES + 63) / 64;                  // 1563
    int agg_blocks  = (N_NODES + 15) / 16;                  // 4 waves/block, 4 nodes/wave

    // --- CSR build overlapped with W prep and GEMM-1 ---
    hipMemsetAsync(bcnt, 0, NBUCK * sizeof(int), stream);
    k_wprep_hist<<<32 + NWG1, 256, 0, stream>>>(W1, W2, Wt, edst, bcnt);
    k_scanN<<<1, 256, 0, stream>>>(bcnt, boff, gcur);
    k_scat_gemm<<<NWG1 + gemm_blocks, 256, 0, stream>>>(esrc, edst, ew, gcur, ebuf,
                                                        x, Wt, hbuf, N_NODES);
    k_sortb<<<NBUCK, 512, 0, stream>>>(ebuf, boff, rowptr);

    // --- layer 1 aggregation ---
    k_agg<true><<<agg_blocks, 256, 0, stream>>>(hbuf, rowptr, ebuf, act1, N_NODES);
    // --- layer 2 ---
    k_gemm2<<<gemm_blocks, 256, 0, stream>>>(act1, Wt + 32768, hbuf, N_NODES);
    k_agg<false><<<agg_blocks, 256, 0, stream>>>(hbuf, rowptr, ebuf, out, N_NODES);
}

// Round 19
// 210.496 us; speedup vs baseline: 1.0982x; 1.0416x over previous
//
#include <hip/hip_runtime.h>
#include <hip/hip_bf16.h>

#define N_NODES 100000
#define N_EDGES 1600000
#define D 128
#define BSZ 128                         // dst nodes per bucket
#define NBUCK 782                       // ceil(N_NODES / BSZ)
#define EPW 4096                        // edges per WG in scatter
#define NWG1 ((N_EDGES + EPW - 1) / EPW)  // 391
#define CAP 4096                        // LDS edge staging per bucket (mean 2048)
#define OTS 272                         // epilogue LDS tile row stride (bytes)

typedef unsigned int  uint4n  __attribute__((ext_vector_type(4)));
typedef float         float4n __attribute__((ext_vector_type(4)));
typedef _Float16      half8n  __attribute__((ext_vector_type(8)));
typedef _Float16      half4n  __attribute__((ext_vector_type(4)));

// swizzled LDS byte offset for element (row, kb): 256B per row, XOR bits 4-7
#define SWZ(row, kb) (((row) << 8) + ((kb) ^ (((row) & 15) << 4)))

// tanh(x) = 1 - 2/(exp2(2*log2e*x)+1); hw exp2+rcp, abs err ~2e-7.
__device__ __forceinline__ float fast_tanh(float x) {
    float t = __builtin_amdgcn_exp2f(x * 2.885390081777927f);
    return 1.0f - 2.0f * __builtin_amdgcn_rcpf(t + 1.0f);
}

// ---------------- W prep: Wt = fp16(W^T) swizzled image (32 blocks) ----------------
__global__ __launch_bounds__(256) void k_wprep(const float* __restrict__ W1,
                                               const float* __restrict__ W2,
                                               char* __restrict__ Wt) {
    const float* W = (blockIdx.x < 16) ? W1 : W2;
    char* dstp = Wt + ((blockIdx.x < 16) ? 0 : 32768);
    int t = (blockIdx.x & 15) * 256 + threadIdx.x;   // 0..4095
    int idx = t * 4;
    int k = idx >> 7, c = idx & 127;
    float4 wv = *(const float4*)&W[idx];
    *(_Float16*)(dstp + SWZ(c + 0, k * 2)) = (_Float16)wv.x;
    *(_Float16*)(dstp + SWZ(c + 1, k * 2)) = (_Float16)wv.y;
    *(_Float16*)(dstp + SWZ(c + 2, k * 2)) = (_Float16)wv.z;
    *(_Float16*)(dstp + SWZ(c + 3, k * 2)) = (_Float16)wv.w;
}

// ---------------- fused: block-local bucket sort (blocks 0..NWG1-1) || GEMM layer 1 ----------
// Scatter role: LDS hist of own 4096 edges -> in-LDS exclusive scan -> write cntM/loffM
// matrices + bucket-grouped records into OWN dense staging region (no global atomics).
// Record: (src<<8 | dst&127, weight) = 8B; src<<8 IS the byte offset of H row.
// GEMM role: H[n x 128](fp16) = X_f32 @ W1, staged fp16 LDS, MFMA 16x16x32.
__global__ __launch_bounds__(256) void k_scat_gemm(const int* __restrict__ src,
                                                   const int* __restrict__ dst,
                                                   const float* __restrict__ ew,
                                                   int2* __restrict__ staging,
                                                   int* __restrict__ cntM,
                                                   int* __restrict__ loffM,
                                                   const float* __restrict__ Xf,
                                                   const char* __restrict__ Wt,
                                                   _Float16* __restrict__ H, int n) {
    __shared__ char smem[17408];
    int tid = threadIdx.x;

    if (blockIdx.x < NWG1) {
        // ---- block-local sort role ----
        int* h   = (int*)smem;            // [NBUCK]
        int* cur = h + NBUCK;             // [NBUCK]
        int* tmp = cur + NBUCK;           // [256]
        int blk  = blockIdx.x;
        for (int i = tid; i < NBUCK; i += 256) h[i] = 0;
        __syncthreads();
        int base = blk * EPW;
        int end  = min(base + EPW, N_EDGES);
        {
            int i = base + tid;
            for (; i + 768 < end; i += 1024) {     // 4 loads in flight
                int d0 = dst[i], d1 = dst[i + 256], d2 = dst[i + 512], d3 = dst[i + 768];
                atomicAdd(&h[d0 >> 7], 1);
                atomicAdd(&h[d1 >> 7], 1);
                atomicAdd(&h[d2 >> 7], 1);
                atomicAdd(&h[d3 >> 7], 1);
            }
            for (; i < end; i += 256)
                atomicAdd(&h[dst[i] >> 7], 1);
        }
        __syncthreads();
        // exclusive scan of h[0..NBUCK) -> cur; write matrices
        int carry = 0;
        for (int c = 0; c < 4; c++) {             // 4*256 = 1024 >= NBUCK
            int i = c * 256 + tid;
            int v = (i < NBUCK) ? h[i] : 0;
            tmp[tid] = v;
            __syncthreads();
            int run = v;
            for (int off = 1; off < 256; off <<= 1) {
                int t = (tid >= off) ? tmp[tid - off] : 0;
                __syncthreads();
                run += t;
                tmp[tid] = run;
                __syncthreads();
            }
            int excl = carry + run - v;
            if (i < NBUCK) {
                cur[i] = excl;
                cntM[blk * NBUCK + i]  = v;
                loffM[blk * NBUCK + i] = excl;
            }
            int tot = tmp[255];
            __syncthreads();
            carry += tot;
        }
        __syncthreads();
        // place records bucket-grouped into own staging region (L2-resident 32KB)
        {
            int2* sg = staging + (size_t)blk * EPW;
            int i = base + tid;
            for (; i + 768 < end; i += 1024) {     // batched loads, 4 indep chains
                int d0 = dst[i], d1 = dst[i + 256], d2 = dst[i + 512], d3 = dst[i + 768];
                int s0 = src[i], s1 = src[i + 256], s2 = src[i + 512], s3 = src[i + 768];
                float w0 = ew[i], w1 = ew[i + 256], w2 = ew[i + 512], w3 = ew[i + 768];
                int p0 = atomicAdd(&cur[d0 >> 7], 1);
                int p1 = atomicAdd(&cur[d1 >> 7], 1);
                int p2 = atomicAdd(&cur[d2 >> 7], 1);
                int p3 = atomicAdd(&cur[d3 >> 7], 1);
                sg[p0] = make_int2((s0 << 8) | (d0 & 127), __float_as_int(w0));
                sg[p1] = make_int2((s1 << 8) | (d1 & 127), __float_as_int(w1));
                sg[p2] = make_int2((s2 << 8) | (d2 & 127), __float_as_int(w2));
                sg[p3] = make_int2((s3 << 8) | (d3 & 127), __float_as_int(w3));
            }
            for (; i < end; i += 256) {
                int d = dst[i];
                int p = atomicAdd(&cur[d >> 7], 1);
                sg[p] = make_int2((src[i] << 8) | (d & 127), __float_as_int(ew[i]));
            }
        }
        return;
    }

    // ---- GEMM layer-1 role ----
    char* sA = smem;
    int lane = tid & 63, w = tid >> 6;
    int rows0 = (blockIdx.x - NWG1) * 64;

    int rb2 = (w >> 1) * 32;     // wave row base within slab (0/32)
    int cb = (w & 1) * 64;       // wave col base (0/64)
    int lr = lane & 15;          // frag row/col within tile
    int kg = (lane >> 4) * 16;   // k-group byte offset

    #pragma unroll
    for (int rep = 0; rep < 8; rep++) {
        int ef = rep * 1024 + tid * 4;
        int r = ef >> 7, c = ef & 127;
        int rg = rows0 + r;
        float4 xv = make_float4(0.f, 0.f, 0.f, 0.f);
        if (rg < n) xv = *(const float4*)(Xf + (size_t)rg * 128 + c);
        half4n hv;
        hv[0] = (_Float16)xv.x; hv[1] = (_Float16)xv.y;
        hv[2] = (_Float16)xv.z; hv[3] = (_Float16)xv.w;
        *(half4n*)(sA + SWZ(r, c * 2)) = hv;
    }
    __syncthreads();

    float4n acc[2][4] = {};
    #pragma unroll
    for (int ks = 0; ks < 4; ks++) {
        half8n bwk[4];
        #pragma unroll
        for (int ct = 0; ct < 4; ct++)
            bwk[ct] = *(const half8n*)(Wt + SWZ(cb + ct * 16 + lr, ks * 64 + kg));
        half8n af[2];
        #pragma unroll
        for (int rt = 0; rt < 2; rt++)
            af[rt] = *(const half8n*)(sA + SWZ(rb2 + rt * 16 + lr, ks * 64 + kg));
        #pragma unroll
        for (int rt = 0; rt < 2; rt++)
            #pragma unroll
            for (int ct = 0; ct < 4; ct++)
                acc[rt][ct] = __builtin_amdgcn_mfma_f32_16x16x32_f16(af[rt], bwk[ct], acc[rt][ct], 0, 0, 0);
    }

    __syncthreads();                              // sA dead, reuse as OT
    char* OT = smem;
    int rloc = rb2 + (lane >> 4) * 4;
    #pragma unroll
    for (int rt = 0; rt < 2; rt++) {
        #pragma unroll
        for (int ct = 0; ct < 4; ct++) {
            int col = cb + ct * 16 + lr;
            #pragma unroll
            for (int r = 0; r < 4; r++)
                *(_Float16*)(OT + (rloc + rt * 16 + r) * OTS + col * 2) = (_Float16)acc[rt][ct][r];
        }
    }
    __syncthreads();
    #pragma unroll
    for (int rep = 0; rep < 4; rep++) {
        int ef = rep * 2048 + tid * 8;
        int r = ef >> 7, c = ef & 127;
        int rg = rows0 + r;
        if (rg < n) {
            half8n v = *(const half8n*)(OT + r * OTS + c * 2);
            *(half8n*)&H[(size_t)rg * 128 + c] = v;
        }
    }
}

// ---------------- column sums of cntM -> bcnt (plain writes, no memset needed) ------------
__global__ __launch_bounds__(256) void k_sumcol(const int* __restrict__ cntM,
                                                int* __restrict__ bcnt) {
    int b = blockIdx.x * 256 + threadIdx.x;
    if (b >= NBUCK) return;
    int s = 0;
    int blk = 0;
    for (; blk + 4 <= NWG1; blk += 4) {
        int a0 = cntM[(size_t)(blk + 0) * NBUCK + b];
        int a1 = cntM[(size_t)(blk + 1) * NBUCK + b];
        int a2 = cntM[(size_t)(blk + 2) * NBUCK + b];
        int a3 = cntM[(size_t)(blk + 3) * NBUCK + b];
        s += a0 + a1 + a2 + a3;
    }
    for (; blk < NWG1; blk++) s += cntM[(size_t)blk * NBUCK + b];
    bcnt[b] = s;
}

// Single-block exclusive scan over NBUCK counts -> boff.
__global__ void k_scanN(const int* __restrict__ bcnt, int* __restrict__ boff) {
    __shared__ int tmp[256];
    int tid = threadIdx.x;
    int carry = 0;
    for (int c = 0; c < (NBUCK + 255) / 256; c++) {
        int i = c * 256 + tid;
        int v = (i < NBUCK) ? bcnt[i] : 0;
        tmp[tid] = v;
        __syncthreads();
        int run = v;
        for (int off = 1; off < 256; off <<= 1) {
            int t = (tid >= off) ? tmp[tid - off] : 0;
            __syncthreads();
            run += t;
            tmp[tid] = run;
            __syncthreads();
        }
        int excl = carry + run - v;
        if (i < NBUCK) boff[i] = excl;
        int tot = tmp[255];
        __syncthreads();
        carry += tot;
    }
    if (tid == 0) boff[NBUCK] = N_EDGES;
}

// ---------------- per-bucket gather (391 runs) + counting sort + rowptr ----------------
__global__ __launch_bounds__(512) void k_sortb(const int2* __restrict__ staging,
                                               const int* __restrict__ cntM,
                                               const int* __restrict__ loffM,
                                               const int* __restrict__ boff,
                                               int2* __restrict__ ebuf,
                                               int* __restrict__ rowptr) {
    __shared__ int2 se[CAP];
    __shared__ int rcs[512];     // inclusive sums of per-blk counts
    __shared__ int rco[512];     // original per-blk counts
    __shared__ int lfs[NWG1];    // per-blk local offsets
    __shared__ int cnt2[BSZ];
    __shared__ int cur2[BSZ];
    int tid = threadIdx.x;
    int b   = blockIdx.x;
    int e0 = boff[b], e1 = boff[b + 1];
    int m  = e1 - e0;
    {
        int v = (tid < NWG1) ? cntM[(size_t)tid * NBUCK + b] : 0;
        rcs[tid] = v;
        rco[tid] = v;
        if (tid < NWG1) lfs[tid] = loffM[(size_t)tid * NBUCK + b];
        if (tid < BSZ) cnt2[tid] = 0;
    }
    __syncthreads();
    // inclusive scan over 512 (Hillis-Steele)
    for (int off = 1; off < 512; off <<= 1) {
        int t = (tid >= off) ? rcs[tid - off] : 0;
        __syncthreads();
        rcs[tid] += t;
        __syncthreads();
    }
    // gather + histogram
    for (int i = tid; i < m; i += 512) {
        int lo = 0, hi = NWG1 - 1;                // first blk with rcs[blk] > i
        while (lo < hi) { int mid = (lo + hi) >> 1; if (rcs[mid] > i) hi = mid; else lo = mid + 1; }
        int blk = lo;
        int within = i - (rcs[blk] - rco[blk]);
        int2 rec = staging[(size_t)blk * EPW + lfs[blk] + within];
        if (i < CAP) se[i] = rec;                 // m <= CAP statistically always
        atomicAdd(&cnt2[rec.x & (BSZ - 1)], 1);
    }
    __syncthreads();
    if (tid < 64) {                               // wave-0 shfl scan of 128 counts
        int a  = cnt2[tid * 2], bq = cnt2[tid * 2 + 1];
        int s  = a + bq;
        int incl = s;
        #pragma unroll
        for (int off = 1; off < 64; off <<= 1) {
            int t = __shfl_up(incl, off, 64);
            if (tid >= off) incl += t;
        }
        int ex = incl - s;                        // exclusive prefix of this pair
        cur2[tid * 2]     = ex;
        cur2[tid * 2 + 1] = ex + a;
        int node = b * BSZ + tid * 2;
        if (node     <= N_NODES) rowptr[node]     = e0 + ex;
        if (node + 1 <= N_NODES) rowptr[node + 1] = e0 + ex + a;
    }
    __syncthreads();
    // place
    for (int i = tid; i < m; i += 512) {
        int2 rec;
        if (i < CAP) rec = se[i];
        else {                                    // rare overflow path: re-gather
            int lo = 0, hi = NWG1 - 1;
            while (lo < hi) { int mid = (lo + hi) >> 1; if (rcs[mid] > i) hi = mid; else lo = mid + 1; }
            int blk = lo;
            rec = staging[(size_t)blk * EPW + lfs[blk] + (i - (rcs[blk] - rco[blk]))];
        }
        int p = atomicAdd(&cur2[rec.x & (BSZ - 1)], 1);
        ebuf[e0 + p] = rec;
    }
}

// ---------------- GEMM (layer 2, fp16 in): staged LDS path ----------------
__global__ __launch_bounds__(256) void k_gemm2(const _Float16* __restrict__ Xh,
                                               const char* __restrict__ Wt,
                                               _Float16* __restrict__ H, int n) {
    __shared__ char smem[17408];
    char* sA = smem;
    int tid  = threadIdx.x;
    int lane = tid & 63, w = tid >> 6;
    int rows0 = blockIdx.x * 64;

    int rb = (w >> 1) * 32;
    int cb = (w & 1) * 64;
    int lr = lane & 15;
    int kg = (lane >> 4) * 16;

    #pragma unroll
    for (int rep = 0; rep < 4; rep++) {
        int ef = rep * 2048 + tid * 8;
        int r = ef >> 7, c = ef & 127;
        int rg = rows0 + r;
        half8n v = half8n(0);
        if (rg < n) v = *(const half8n*)(Xh + (size_t)rg * 128 + c);
        *(half8n*)(sA + SWZ(r, c * 2)) = v;
    }
    __syncthreads();

    float4n acc[2][4] = {};
    #pragma unroll
    for (int ks = 0; ks < 4; ks++) {
        half8n bwk[4];
        #pragma unroll
        for (int ct = 0; ct < 4; ct++)
            bwk[ct] = *(const half8n*)(Wt + SWZ(cb + ct * 16 + lr, ks * 64 + kg));
        half8n af[2];
        #pragma unroll
        for (int rt = 0; rt < 2; rt++)
            af[rt] = *(const half8n*)(sA + SWZ(rb + rt * 16 + lr, ks * 64 + kg));
        #pragma unroll
        for (int rt = 0; rt < 2; rt++)
            #pragma unroll
            for (int ct = 0; ct < 4; ct++)
                acc[rt][ct] = __builtin_amdgcn_mfma_f32_16x16x32_f16(af[rt], bwk[ct], acc[rt][ct], 0, 0, 0);
    }

    __syncthreads();
    char* OT = smem;
    int rloc = rb + (lane >> 4) * 4;
    #pragma unroll
    for (int rt = 0; rt < 2; rt++) {
        #pragma unroll
        for (int ct = 0; ct < 4; ct++) {
            int col = cb + ct * 16 + lr;
            #pragma unroll
            for (int r = 0; r < 4; r++)
                *(_Float16*)(OT + (rloc + rt * 16 + r) * OTS + col * 2) = (_Float16)acc[rt][ct][r];
        }
    }
    __syncthreads();
    #pragma unroll
    for (int rep = 0; rep < 4; rep++) {
        int ef = rep * 2048 + tid * 8;
        int r = ef >> 7, c = ef & 127;
        int rg = rows0 + r;
        if (rg < n) {
            half8n v = *(const half8n*)(OT + r * OTS + c * 2);
            *(half8n*)&H[(size_t)rg * 128 + c] = v;
        }
    }
}

// ---------------- Aggregation: out[n] = tanh(sum_e w_e * H[src_e]) ----------------
// FOUR nodes per wave (16-lane group per node). Inner loop keeps FOUR gathers
// in flight: load 4 edge records first, then issue 4 H-row gathers, then FMAs.
template<bool OUTF16>
__global__ __launch_bounds__(256) void k_agg(const _Float16* __restrict__ H,
                                             const int* __restrict__ rowptr,
                                             const int2* __restrict__ ebuf,
                                             void* __restrict__ outv, int n) {
    int wv   = (blockIdx.x * 256 + threadIdx.x) >> 6;   // global wave index
    int lane = threadIdx.x & 63;
    int g = lane >> 4;                 // node slot within wave (0..3)
    int c = lane & 15;                 // columns c*8 .. c*8+7 (16B of the row)
    int node = wv * 4 + g;
    if (node >= n) return;
    const char* Hc = (const char*)H + (c << 4);   // per-lane column base
    int e0 = rowptr[node], e1 = rowptr[node + 1];
    float acc[8] = {};
    int e = e0;
    for (; e + 4 <= e1; e += 4) {                 // 4 gathers in flight
        int2 d0 = ebuf[e];
        int2 d1 = ebuf[e + 1];
        int2 d2 = ebuf[e + 2];
        int2 d3 = ebuf[e + 3];
        half8n v0 = *(const half8n*)(Hc + (size_t)((unsigned)d0.x & 0xFFFFFF00u));
        half8n v1 = *(const half8n*)(Hc + (size_t)((unsigned)d1.x & 0xFFFFFF00u));
        half8n v2 = *(const half8n*)(Hc + (size_t)((unsigned)d2.x & 0xFFFFFF00u));
        half8n v3 = *(const half8n*)(Hc + (size_t)((unsigned)d3.x & 0xFFFFFF00u));
        float w0 = __int_as_float(d0.y);
        float w1 = __int_as_float(d1.y);
        float w2 = __int_as_float(d2.y);
        float w3 = __int_as_float(d3.y);
        #pragma unroll
        for (int j = 0; j < 8; j++) acc[j] = __builtin_fmaf((float)v0[j], w0, acc[j]);
        #pragma unroll
        for (int j = 0; j < 8; j++) acc[j] = __builtin_fmaf((float)v1[j], w1, acc[j]);
        #pragma unroll
        for (int j = 0; j < 8; j++) acc[j] = __builtin_fmaf((float)v2[j], w2, acc[j]);
        #pragma unroll
        for (int j = 0; j < 8; j++) acc[j] = __builtin_fmaf((float)v3[j], w3, acc[j]);
    }
    for (; e < e1; ++e) {
        int2 ed = ebuf[e];
        half8n v = *(const half8n*)(Hc + (size_t)((unsigned)ed.x & 0xFFFFFF00u));
        float w = __int_as_float(ed.y);
        #pragma unroll
        for (int j = 0; j < 8; j++) acc[j] = __builtin_fmaf((float)v[j], w, acc[j]);
    }
    if (OUTF16) {
        half8n hv;
        #pragma unroll
        for (int j = 0; j < 8; j++) hv[j] = (_Float16)fast_tanh(acc[j]);
        // plain store: act1 is re-read by the next GEMM, keep it cache-resident
        *(uint4n*)((_Float16*)outv + (size_t)node * 128 + c * 8) = *(uint4n*)&hv;
    } else {
        float* op = (float*)outv + (size_t)node * 128 + c * 8;
        float4n o0, o1;
        o0.x = fast_tanh(acc[0]); o0.y = fast_tanh(acc[1]);
        o0.z = fast_tanh(acc[2]); o0.w = fast_tanh(acc[3]);
        o1.x = fast_tanh(acc[4]); o1.y = fast_tanh(acc[5]);
        o1.z = fast_tanh(acc[6]); o1.w = fast_tanh(acc[7]);
        __builtin_nontemporal_store(o0, (float4n*)op);
        __builtin_nontemporal_store(o1, (float4n*)(op + 4));
    }
}

// ---------------- launch ----------------

extern "C" void kernel_launch(void* const* d_in, const int* in_sizes, int n_in,
                              void* d_out, int out_size, void* d_ws, size_t ws_size,
                              hipStream_t stream) {
    const float* x    = (const float*)d_in[0];
    const int*   esrc = (const int*)d_in[1];
    const int*   edst = (const int*)d_in[2];
    const float* ew   = (const float*)d_in[3];
    const float* W1   = (const float*)d_in[4];
    const float* W2   = (const float*)d_in[5];
    float* out = (float*)d_out;

    // Workspace layout (~64.6 MB):
    _Float16* hbuf = (_Float16*)d_ws;                      // N*D fp16 (25.6 MB)
    _Float16* act1 = hbuf + (size_t)N_NODES * D;           // N*D fp16 (25.6 MB)
    // staging + matrices live INSIDE the act1 region (consumed before agg1 writes act1):
    int2* staging  = (int2*)act1;                          // NWG1*EPW int2 (12.81 MB)
    int*  cntM     = (int*)(staging + (size_t)NWG1 * EPW); // NWG1*NBUCK (1.22 MB)
    int*  loffM    = cntM + (size_t)NWG1 * NBUCK;          // NWG1*NBUCK (1.22 MB)
    int2* ebuf     = (int2*)(act1 + (size_t)N_NODES * D);  // E int2 (12.8 MB)
    int*  bcnt     = (int*)(ebuf + N_EDGES);               // NBUCK
    int*  boff     = bcnt + NBUCK;                         // NBUCK+1
    int*  rowptr   = boff + (NBUCK + 2);                   // N+1 ints (0.4 MB)
    char* Wt       = (char*)(rowptr + N_NODES + 8);        // 64 KB (two 32KB blobs)
    (void)ws_size; (void)in_sizes; (void)n_in; (void)out_size;

    int gemm_blocks = (N_NODES + 63) / 64;                  // 1563
    int agg_blocks  = (N_NODES + 15) / 16;                  // 4 waves/block, 4 nodes/wave

    // --- W prep, then CSR block-local sort overlapped with GEMM-1 ---
    k_wprep<<<32, 256, 0, stream>>>(W1, W2, Wt);
    k_scat_gemm<<<NWG1 + gemm_blocks, 256, 0, stream>>>(esrc, edst, ew,
                                                        staging, cntM, loffM,
                                                        x, Wt, hbuf, N_NODES);
    k_sumcol<<<(NBUCK + 255) / 256, 256, 0, stream>>>(cntM, bcnt);
    k_scanN<<<1, 256, 0, stream>>>(bcnt, boff);
    k_sortb<<<NBUCK, 512, 0, stream>>>(staging, cntM, loffM, boff, ebuf, rowptr);

    // --- layer 1 aggregation (overwrites act1/staging region — staging already consumed) ---
    k_agg<true><<<agg_blocks, 256, 0, stream>>>(hbuf, rowptr, ebuf, act1, N_NODES);
    // --- layer 2 ---
    k_gemm2<<<gemm_blocks, 256, 0, stream>>>(act1, Wt + 32768, hbuf, N_NODES);
    k_agg<false><<<agg_blocks, 256, 0, stream>>>(hbuf, rowptr, ebuf, out, N_NODES);
}